// Round 11
// baseline (306.671 us; speedup 1.0000x reference)
//
#include <hip/hip_runtime.h>

typedef unsigned short u16;
typedef unsigned int   u32;
typedef __attribute__((ext_vector_type(8))) short s16x8;   // 8 x bf16 payload (4 VGPRs)
typedef __attribute__((ext_vector_type(4))) float f32x4;   // MFMA accumulator / f32 quad
typedef __attribute__((ext_vector_type(16))) float f32x16; // 32x32 MFMA accumulator

#define MFMA16(a, b, c) __builtin_amdgcn_mfma_f32_16x16x32_bf16((a), (b), (c), 0, 0, 0)
#define MFMA32(a, b, c) __builtin_amdgcn_mfma_f32_32x32x16_bf16((a), (b), (c), 0, 0, 0)
#define EXP2R(x) __builtin_amdgcn_exp2f(x)   // raw v_exp_f32 (no libm fixup)

// async global->LDS, 16B per lane. LDS dest is wave-uniform base + lane*16
// (m104/m108); our staging layouts are linear in lane (tid*16B), so base =
// buf + region + w*512 u16.
#define GLD16(gp, lp) __builtin_amdgcn_global_load_lds(                     \
    (const __attribute__((address_space(1))) void*)(gp),                    \
    (__attribute__((address_space(3))) void*)(lp), 16, 0, 0)

// ws layout (bf16 elements): [PW_bf16: 1,048,576][Qc|Kc|Vc: 3*segE][AO if HG<16]
// Fast path (ws >= 75.5MB, HG16): + [Xb: 8,388,608][Wb: 3,145,728] after Vc.
// FRAGMENT-MAJOR layouts (so k_attn hot-loop loads are contiguous 1KB/wave):
//  Qc: [p][qt32 (64)][ks (4)][lane (64)][8]   qt32 = 32-token q tile
//  Kc: [p][kt (32)][ks*2+kb (8)][lane (64)][8]
//  Vc: [p][kt (32)][ks*2+db (8)][lane (64)][8]
#define PWOFF 1048576ull

__device__ __forceinline__ u16 f2b(float f) {
  union { float f; unsigned i; } x; x.f = f;
  unsigned r = x.i + 0x7FFFu + ((x.i >> 16) & 1u);
  return (u16)(r >> 16);
}
__device__ __forceinline__ u32 cvtpk_bf16(float a, float b) {
  u32 r;
  asm("v_cvt_pk_bf16_f32 %0, %1, %2" : "=v"(r) : "v"(a), "v"(b));
  return r;
}
// fp32x8 -> bf16x8 via v_cvt_pk_bf16_f32 (RNE, bit-identical to f2b).
__device__ __forceinline__ s16x8 cvt8(const float* __restrict__ p) {
  f32x4 a = *(const f32x4*)p;
  f32x4 b = *(const f32x4*)(p + 4);
  union { u32 u[4]; s16x8 v; } o;
  o.u[0] = cvtpk_bf16(a[0], a[1]);
  o.u[1] = cvtpk_bf16(a[2], a[3]);
  o.u[2] = cvtpk_bf16(b[0], b[1]);
  o.u[3] = cvtpk_bf16(b[2], b[3]);
  return o.v;
}

__device__ __forceinline__ void plswap(u32& a, u32& b) {
#if __has_builtin(__builtin_amdgcn_permlane32_swap)
  auto r = __builtin_amdgcn_permlane32_swap(a, b, false, false);
  a = r[0]; b = r[1];
#else
  asm volatile("v_permlane32_swap_b32 %0, %1" : "+v"(a), "+v"(b));
#endif
}
// Cross-half (lane <-> lane^32) partner fetch, VALU-only.
__device__ __forceinline__ float pair32(float x, int hi) {
  union { float f; u32 u; } a, b;
  a.f = x; b.f = x;
  plswap(a.u, b.u);
  return hi ? a.f : b.f;
}
// Build PV A-fragment (contraction slice of 16 k) from 8 packed f32 P values.
// Lane holds P[k = crow(r,hi)] with crow = (r&3)+8*(r>>2)+4*hi; the swap gives
// lanes l<->l+32 each other's missing half: frag words (k0k1)(k2k3)(k4k5)(k6k7).
__device__ __forceinline__ s16x8 mk_pa(float e0, float e1, float e2, float e3,
                                       float e4, float e5, float e6, float e7) {
  u32 a0 = cvtpk_bf16(e0, e1), b0 = cvtpk_bf16(e4, e5);
  u32 a1 = cvtpk_bf16(e2, e3), b1 = cvtpk_bf16(e6, e7);
  plswap(a0, b0);
  plswap(a1, b1);
  union { u32 u[4]; s16x8 v; } x;
  x.u[0] = a0; x.u[1] = a1; x.u[2] = b0; x.u[3] = b1;
  return x.v;
}

// exp2 + pack + partial-sum for one group of 8 score elements (streamed: ~8
// live pv floats instead of 32).
#define SM_GRP(sv, ofs, pa_out, ps_out) {                                  \
    float e0 = EXP2R((sv)[(ofs) + 0] * C - mC);                            \
    float e1 = EXP2R((sv)[(ofs) + 1] * C - mC);                            \
    float e2 = EXP2R((sv)[(ofs) + 2] * C - mC);                            \
    float e3 = EXP2R((sv)[(ofs) + 3] * C - mC);                            \
    float e4 = EXP2R((sv)[(ofs) + 4] * C - mC);                            \
    float e5 = EXP2R((sv)[(ofs) + 5] * C - mC);                            \
    float e6 = EXP2R((sv)[(ofs) + 6] * C - mC);                            \
    float e7 = EXP2R((sv)[(ofs) + 7] * C - mC);                            \
    (pa_out) = mk_pa(e0, e1, e2, e3, e4, e5, e6, e7);                      \
    (ps_out) = ((e0 + e1) + (e2 + e3)) + ((e4 + e5) + (e6 + e7));          \
  }

// ---------------------------------------------------------------------------
// Beacon (only if ws too small for any path): fill d_out with 3000+wsMB.
// ---------------------------------------------------------------------------
__global__ void k_beacon(float* __restrict__ Out, unsigned long long ws_size) {
  float V = 3000.0f + fminf((float)(ws_size >> 20), 999.0f);
  size_t i = ((size_t)blockIdx.x * 256 + threadIdx.x) * 8;
#pragma unroll
  for (int j = 0; j < 8; ++j) Out[i + j] = V;
}

// ---------------------------------------------------------------------------
// proj_w fp32 [1024,1024] -> bf16 at ws[0..1048576)
// ---------------------------------------------------------------------------
__global__ void k_convert_pw(const float* __restrict__ PW, u16* __restrict__ ws) {
  size_t i = ((size_t)blockIdx.x * 256 + threadIdx.x) * 8;
  *(s16x8*)(ws + i) = cvt8(PW + i);
}

// ---------------------------------------------------------------------------
// Fast path: X [8192,1024] fp32 and QKVW [3072,1024] fp32 -> bf16 at dst
// (Xb then Wb contiguously). grid 5632 x 256 x 8 elems = 11,534,336.
// ---------------------------------------------------------------------------
__global__ void k_convert_xw(const float* __restrict__ X,
                             const float* __restrict__ W,
                             u16* __restrict__ dst) {
  size_t i = ((size_t)blockIdx.x * 256 + threadIdx.x) * 8;
  const float* src = (i < 8388608ull) ? (X + i) : (W + (i - 8388608ull));
  *(s16x8*)(dst + i) = cvt8(src);
}

// raw f32 loads for one 32-wide K-slice of the qkv GEMM staging (issue-early)
#define QLOAD(K) {                                                 \
    la0 = *(const f32x4*)(Ag + (K));                               \
    la1 = *(const f32x4*)(Ag + (K) + 4);                           \
    lb0 = *(const f32x4*)(Ag + (size_t)64 * 1024 + (K));           \
    lb1 = *(const f32x4*)(Ag + (size_t)64 * 1024 + (K) + 4);       \
    lc0 = *(const f32x4*)(BgA + (K));                              \
    lc1 = *(const f32x4*)(BgA + (K) + 4);                          \
    ld0 = *(const f32x4*)(BgB + (K));                              \
    ld1 = *(const f32x4*)(BgB + (K) + 4);                          \
  }
// convert + LDS-write (write-late: vmcnt waits land here, after the MFMAs)
#define QWRITE(BUF) {                                                         \
    union { u32 u[4]; s16x8 v; } t0, t1, t2, t3;                              \
    t0.u[0] = cvtpk_bf16(la0[0], la0[1]); t0.u[1] = cvtpk_bf16(la0[2], la0[3]); \
    t0.u[2] = cvtpk_bf16(la1[0], la1[1]); t0.u[3] = cvtpk_bf16(la1[2], la1[3]); \
    t1.u[0] = cvtpk_bf16(lb0[0], lb0[1]); t1.u[1] = cvtpk_bf16(lb0[2], lb0[3]); \
    t1.u[2] = cvtpk_bf16(lb1[0], lb1[1]); t1.u[3] = cvtpk_bf16(lb1[2], lb1[3]); \
    t2.u[0] = cvtpk_bf16(lc0[0], lc0[1]); t2.u[1] = cvtpk_bf16(lc0[2], lc0[3]); \
    t2.u[2] = cvtpk_bf16(lc1[0], lc1[1]); t2.u[3] = cvtpk_bf16(lc1[2], lc1[3]); \
    t3.u[0] = cvtpk_bf16(ld0[0], ld0[1]); t3.u[1] = cvtpk_bf16(ld0[2], ld0[3]); \
    t3.u[2] = cvtpk_bf16(ld1[0], ld1[1]); t3.u[3] = cvtpk_bf16(ld1[2], ld1[3]); \
    *(s16x8*)&(BUF)[srow * 32 + scol]               = t0.v;                   \
    *(s16x8*)&(BUF)[(srow + 64) * 32 + scol]        = t1.v;                   \
    *(s16x8*)&(BUF)[4096 + srow * 32 + scol]        = t2.v;                   \
    *(s16x8*)&(BUF)[4096 + (srow + 64) * 32 + scol] = t3.v;                   \
  }

// fast-path async staging: 4 x global_load_lds(16B) per thread per K-step.
// LDS regions (u16): a0 @0, a1 @2048, b0 @4096, b1 @6144; each wave's 1KB
// slice is linear in lane (tid*16B) -> base = BUF + region + w*512.
#define QISSUEB(K, BUF) {                                          \
    GLD16(Agb + (K),          (BUF) + w * 512);                    \
    GLD16(Agb + 65536 + (K),  (BUF) + 2048 + w * 512);             \
    GLD16(BgAb + (K),         (BUF) + 4096 + w * 512);             \
    GLD16(BgBb + (K),         (BUF) + 6144 + w * 512);             \
  }

// Shared epilogue for both qkv variants (bias + RoPE + fragment-major stores).
#define QKV_EPILOGUE                                                          \
  const int ncol = n0 + wc * 64;              /* 64-aligned (which,hh) */     \
  const int which = ncol >> lgHB;             /* 0=q 1=k 2=v */               \
  const int hh = (ncol & (HB - 1)) >> 6;                                      \
  const int cb = which * 1024 + (h0 + hh) * 64;                               \
  const int mbase = m0 + wr * 64;                                             \
  float bias[4];                                                              \
  _Pragma("unroll")                                                           \
  for (int j = 0; j < 4; ++j) bias[j] = Bias[cb + j * 16 + l16];              \
  __syncthreads();                                                            \
  u16* OSt = smem + w * 4608;                                                 \
  if (which == 2) {                                                           \
    _Pragma("unroll")                                                         \
    for (int i = 0; i < 4; ++i)                                               \
      _Pragma("unroll")                                                       \
      for (int r = 0; r < 4; ++r) {                                           \
        int tl = i * 16 + quad * 4 + r;                                       \
        _Pragma("unroll")                                                     \
        for (int j = 0; j < 4; ++j)                                           \
          OSt[(j * 16 + l16) * 72 + tl] = f2b(acc[i][j][r] + bias[j]);        \
      }                                                                       \
  } else {                                                                    \
    const float LC = 0.1716750968f;                                           \
    float fr0 = exp2f((float)l16 * LC);                                       \
    float fr1 = exp2f((float)(16 + l16) * LC);                                \
    _Pragma("unroll")                                                         \
    for (int i = 0; i < 4; ++i)                                               \
      _Pragma("unroll")                                                       \
      for (int r = 0; r < 4; ++r) {                                           \
        int tl = i * 16 + quad * 4 + r;                                       \
        int tok = mbase + tl;                                                 \
        float ps = (float)(tok & 2047) * (1.0f / 2048.0f);                    \
        float rv0 = ps * fr0; rv0 -= floorf(rv0);                             \
        float rv1 = ps * fr1; rv1 -= floorf(rv1);                             \
        float s0 = __builtin_amdgcn_sinf(rv0), c0 = __builtin_amdgcn_cosf(rv0); \
        float s1 = __builtin_amdgcn_sinf(rv1), c1 = __builtin_amdgcn_cosf(rv1); \
        float x10 = acc[i][0][r] + bias[0], x11 = acc[i][1][r] + bias[1];     \
        float x20 = acc[i][2][r] + bias[2], x21 = acc[i][3][r] + bias[3];     \
        OSt[tl * 72 + l16]      = f2b(x10 * c0 - x20 * s0);                   \
        OSt[tl * 72 + 16 + l16] = f2b(x11 * c1 - x21 * s1);                   \
        OSt[tl * 72 + 32 + l16] = f2b(x10 * s0 + x20 * c0);                   \
        OSt[tl * 72 + 48 + l16] = f2b(x11 * s1 + x21 * c1);                   \
      }                                                                       \
  }                                                                           \
  const int bb = mbase >> 11, tt0 = mbase & 2047;                             \
  const int pp = (bb << lgHG) + hh;                                           \
  if (which == 2) {                                                           \
    u16* D = Vc + ((size_t)pp * 32 + (tt0 >> 6)) * 4096;                      \
    _Pragma("unroll")                                                         \
    for (int fi = 0; fi < 8; ++fi) {                                          \
      int ks = fi >> 1, db = fi & 1;                                          \
      *(s16x8*)&D[fi * 512 + lane * 8] =                                      \
          *(const s16x8*)&OSt[(db * 32 + l31) * 72 + ks * 16 + hi * 8];       \
    }                                                                         \
  } else if (which == 1) {                                                    \
    u16* D = Kc + ((size_t)pp * 32 + (tt0 >> 6)) * 4096;                      \
    _Pragma("unroll")                                                         \
    for (int fi = 0; fi < 8; ++fi) {                                          \
      int ks = fi >> 1, kb = fi & 1;                                          \
      *(s16x8*)&D[fi * 512 + lane * 8] =                                      \
          *(const s16x8*)&OSt[(kb * 32 + l31) * 72 + ks * 16 + hi * 8];       \
    }                                                                         \
  } else {                                                                    \
    u16* D = Qc + ((size_t)pp * 64 + (tt0 >> 5)) * 2048;                      \
    _Pragma("unroll")                                                         \
    for (int fi = 0; fi < 8; ++fi) {                                          \
      int qh = fi >> 2, ks = fi & 3;                                          \
      *(s16x8*)&D[(size_t)qh * 2048 + ks * 512 + lane * 8] =                  \
          *(const s16x8*)&OSt[(qh * 32 + l31) * 72 + ks * 16 + hi * 8];       \
    }                                                                         \
  }

// ---------------------------------------------------------------------------
// Kernel 1 (slow path, byte-equivalent to r8): fp32 in, cvt in staging.
// grid ((3*HG)/2, 64), 256 thr. LDS dbuf, one barrier/K-step.
// ---------------------------------------------------------------------------
__global__ __launch_bounds__(256, 4) void k_qkv_rope(
    const float* __restrict__ X, const float* __restrict__ W,
    const float* __restrict__ Bias, u16* __restrict__ ws,
    int h0, int lgHB, int lgHG)
{
  __shared__ __align__(16) u16 smem[18432];   // dbuf 2x(As4096|Bs4096) | epi 4x(64x72)

  const size_t segE = 524288ull << lgHG;
  u16* Qc = ws + PWOFF;
  u16* Kc = Qc + segE;
  u16* Vc = Kc + segE;

  const int tid = threadIdx.x;
  const int w = tid >> 6, lane = tid & 63, quad = lane >> 4, l16 = lane & 15;
  const int l31 = lane & 31, hi = lane >> 5;
  const int wr = w >> 1, wc = w & 1;
  const int HB = 1 << lgHB;

  const int gx = gridDim.x;
  const int hw = blockIdx.y * gx + blockIdx.x;
  const int cpx = (gx << 6) >> 3;             // nwg/8
  const int lg = (hw & 7) * cpx + (hw >> 3);
  const int m0 = (lg / gx) * 128, n0 = (lg % gx) * 128;

  const f32x4 z4 = {0.f, 0.f, 0.f, 0.f};
  f32x4 acc[4][4];
#pragma unroll
  for (int i = 0; i < 4; ++i)
#pragma unroll
    for (int j = 0; j < 4; ++j) acc[i][j] = z4;

  const int srow = tid >> 2;
  const int scol = (tid & 3) * 8;
  const int nlogA = n0 + srow, nlogB = nlogA + 64;
  const int wrowA = (nlogA >> lgHB) * 1024 + (h0 + ((nlogA & (HB - 1)) >> 6)) * 64 + (nlogA & 63);
  const int wrowB = (nlogB >> lgHB) * 1024 + (h0 + ((nlogB & (HB - 1)) >> 6)) * 64 + (nlogB & 63);
  const float* Ag  = X + (size_t)(m0 + srow) * 1024 + scol;
  const float* BgA = W + (size_t)wrowA * 1024 + scol;
  const float* BgB = W + (size_t)wrowB * 1024 + scol;

  f32x4 la0, la1, lb0, lb1, lc0, lc1, ld0, ld1;
  QLOAD(0)
  QWRITE(smem)

  for (int k0 = 0; k0 < 1024; k0 += 32) {
    u16* Ac = smem + ((k0 >> 5) & 1) * 8192;
    if (k0 < 992) QLOAD(k0 + 32)          // issue-early
    __syncthreads();                       // buf[cur] visible; buf[cur^1] free
    s16x8 af[4], bf[4];
#pragma unroll
    for (int i = 0; i < 4; ++i)
      af[i] = *(const s16x8*)&Ac[(wr * 64 + i * 16 + l16) * 32 + quad * 8];
#pragma unroll
    for (int j = 0; j < 4; ++j)
      bf[j] = *(const s16x8*)&Ac[4096 + (wc * 64 + j * 16 + l16) * 32 + quad * 8];
#pragma unroll
    for (int i = 0; i < 4; ++i)
#pragma unroll
      for (int j = 0; j < 4; ++j)
        acc[i][j] = MFMA16(af[i], bf[j], acc[i][j]);
    if (k0 < 992) {
      u16* An = smem + ((~(k0 >> 5)) & 1) * 8192;
      QWRITE(An)                           // cvt+write late
    }
  }

  QKV_EPILOGUE
}

// ---------------------------------------------------------------------------
// Kernel 1b (fast path): bf16 X/W pre-converted -> async global_load_lds
// staging (m97 pattern: barrier -> issue into buf[next] -> ds_read buf[cur]
// -> MFMA; next barrier drains). One instr per 16B, no VGPR round-trip.
// ---------------------------------------------------------------------------
__global__ __launch_bounds__(256, 4) void k_qkv_rope_b(
    const u16* __restrict__ Xb, const u16* __restrict__ Wb,
    const float* __restrict__ Bias, u16* __restrict__ ws,
    int h0, int lgHB, int lgHG)
{
  __shared__ __align__(16) u16 smem[18432];   // dbuf 2x(As4096|Bs4096) | epi 4x(64x72)

  const size_t segE = 524288ull << lgHG;
  u16* Qc = ws + PWOFF;
  u16* Kc = Qc + segE;
  u16* Vc = Kc + segE;

  const int tid = threadIdx.x;
  const int w = tid >> 6, lane = tid & 63, quad = lane >> 4, l16 = lane & 15;
  const int l31 = lane & 31, hi = lane >> 5;
  const int wr = w >> 1, wc = w & 1;
  const int HB = 1 << lgHB;

  const int gx = gridDim.x;
  const int hw = blockIdx.y * gx + blockIdx.x;
  const int cpx = (gx << 6) >> 3;             // nwg/8
  const int lg = (hw & 7) * cpx + (hw >> 3);
  const int m0 = (lg / gx) * 128, n0 = (lg % gx) * 128;

  const f32x4 z4 = {0.f, 0.f, 0.f, 0.f};
  f32x4 acc[4][4];
#pragma unroll
  for (int i = 0; i < 4; ++i)
#pragma unroll
    for (int j = 0; j < 4; ++j) acc[i][j] = z4;

  const int srow = tid >> 2;
  const int scol = (tid & 3) * 8;
  const int nlogA = n0 + srow, nlogB = nlogA + 64;
  const int wrowA = (nlogA >> lgHB) * 1024 + (h0 + ((nlogA & (HB - 1)) >> 6)) * 64 + (nlogA & 63);
  const int wrowB = (nlogB >> lgHB) * 1024 + (h0 + ((nlogB & (HB - 1)) >> 6)) * 64 + (nlogB & 63);
  const u16* Agb  = Xb + (size_t)(m0 + srow) * 1024 + scol;
  const u16* BgAb = Wb + (size_t)wrowA * 1024 + scol;
  const u16* BgBb = Wb + (size_t)wrowB * 1024 + scol;

  // prologue: async-stage tile 0 into buf 0
  QISSUEB(0, smem)

  for (int k0 = 0; k0 < 1024; k0 += 32) {
    u16* Ac = smem + ((k0 >> 5) & 1) * 8192;
    __syncthreads();                       // drains buf[cur] loads; frees other
    if (k0 < 992) {
      u16* An = smem + ((~(k0 >> 5)) & 1) * 8192;
      QISSUEB(k0 + 32, An)                 // async, overlaps MFMA below
    }
    s16x8 af[4], bf[4];
#pragma unroll
    for (int i = 0; i < 4; ++i)
      af[i] = *(const s16x8*)&Ac[(wr * 64 + i * 16 + l16) * 32 + quad * 8];
#pragma unroll
    for (int j = 0; j < 4; ++j)
      bf[j] = *(const s16x8*)&Ac[4096 + (wc * 64 + j * 16 + l16) * 32 + quad * 8];
#pragma unroll
    for (int i = 0; i < 4; ++i)
#pragma unroll
      for (int j = 0; j < 4; ++j)
        acc[i][j] = MFMA16(af[i], bf[j], acc[i][j]);
  }

  QKV_EPILOGUE
}

// ---------------------------------------------------------------------------
// Kernel 2: flash attention — byte-exact r4 body (proven, 128 µs). Two
// scheduling restructures (r5 rotation, r9 straight-line pair) both failed
// correctness in the >128-VGPR regime; this kernel stays at VGPR=64/(256,4).
// grid (16, 4*HG), 256 thr (4 indep waves, 32 q-rows each).
// ---------------------------------------------------------------------------
__global__ __launch_bounds__(256, 4) void k_attn(
    u16* __restrict__ ws, u16* __restrict__ AO, int h0, int lgHG)
{
  __shared__ float redL[4][32];          // per-wave alpha / inv-li broadcast

  const size_t segE = 524288ull << lgHG;
  const u16* Qg = ws + PWOFF;
  const u16* Kg = Qg + segE;
  const u16* Vg = Kg + segE;

  const int tid = threadIdx.x;
  const int w = tid >> 6, lane = tid & 63;
  const int l31 = lane & 31, hi = lane >> 5;

  // XCD swizzle: n = by*16 + bx; xcd = n&7 gets heads [xcd*P/8, ...)
  const int P = 4 << lgHG;
  const int n = blockIdx.y * 16 + blockIdx.x;
  const int mm = n >> 3;
  const int p  = (n & 7) * (P >> 3) + (mm >> 4);
  const int qt = mm & 15;

  const u16* Kb = Kg + (size_t)p * 131072;
  const u16* Vb = Vg + (size_t)p * 131072;
  const int q0 = qt * 128 + w * 32;

  // Q fragments: frag-major, contiguous per wave
  const u16* Qt = Qg + (size_t)p * 131072 + (size_t)(qt * 4 + w) * 2048;
  s16x8 qf[4];
#pragma unroll
  for (int ks = 0; ks < 4; ++ks)
    qf[ks] = *(const s16x8*)&Qt[ks * 512 + lane * 8];

  f32x16 o0, o1;                         // O[q=crow(r,hi)][d=l31 (+32)]
#pragma unroll
  for (int r = 0; r < 16; ++r) { o0[r] = 0.f; o1[r] = 0.f; }
  float m_r = -1e30f, li = 0.f;
  const float C = 0.1803368801f;         // 0.125 * log2(e)

  for (int kt = 0; kt < 32; ++kt) {
    const u16* Kt = Kb + (size_t)kt * 4096;
    const u16* Vt = Vb + (size_t)kt * 4096;
    s16x8 kfA[4], kfB[4], vfA[4], vfB[4];
#pragma unroll
    for (int ks = 0; ks < 4; ++ks) {
      kfA[ks] = *(const s16x8*)&Kt[(ks * 2 + 0) * 512 + lane * 8];
      kfB[ks] = *(const s16x8*)&Kt[(ks * 2 + 1) * 512 + lane * 8];
    }
#pragma unroll
    for (int ks = 0; ks < 4; ++ks) {
      vfA[ks] = *(const s16x8*)&Vt[(ks * 2 + 0) * 512 + lane * 8];
      vfB[ks] = *(const s16x8*)&Vt[(ks * 2 + 1) * 512 + lane * 8];
    }

    // swapped QK^T: C[row = k-local = crow(r,hi)][col = q = l31]
    f32x16 s0, s1;
#pragma unroll
    for (int r = 0; r < 16; ++r) { s0[r] = 0.f; s1[r] = 0.f; }
#pragma unroll
    for (int ks = 0; ks < 4; ++ks) {
      s0 = MFMA32(kfA[ks], qf[ks], s0);
      s1 = MFMA32(kfB[ks], qf[ks], s1);
    }

    // tree max over the 32 locally-held scores (depth ~5, v_max3-friendly)
    float m8[8];
#pragma unroll
    for (int r = 0; r < 8; ++r)
      m8[r] = fmaxf(fmaxf(s0[r], s0[r + 8]), fmaxf(s1[r], s1[r + 8]));
    float mx = fmaxf(fmaxf(fmaxf(m8[0], m8[1]), fmaxf(m8[2], m8[3])),
                     fmaxf(fmaxf(m8[4], m8[5]), fmaxf(m8[6], m8[7])));
    mx = fmaxf(mx, pair32(mx, hi));

    // defer-max: rescale O only when max grew past THR (wave-uniform branch)
    if (!__all(mx - m_r <= 8.0f)) {
      float mnew = fmaxf(m_r, mx);
      float al = EXP2R((m_r - mnew) * C);
      m_r = mnew;
      li *= al;
      if (hi == 0) redL[w][l31] = al;    // alpha[q] at q=l31
      f32x4 a0 = *(const f32x4*)&redL[w][hi * 4];       // crow rows 8g+4hi+e
      f32x4 a1 = *(const f32x4*)&redL[w][8 + hi * 4];
      f32x4 a2 = *(const f32x4*)&redL[w][16 + hi * 4];
      f32x4 a3 = *(const f32x4*)&redL[w][24 + hi * 4];
#pragma unroll
      for (int e = 0; e < 4; ++e) {
        o0[e]      *= a0[e];  o1[e]      *= a0[e];
        o0[4 + e]  *= a1[e];  o1[4 + e]  *= a1[e];
        o0[8 + e]  *= a2[e];  o1[8 + e]  *= a2[e];
        o0[12 + e] *= a3[e];  o1[12 + e] *= a3[e];
      }
    }

    const float mC = m_r * C;
    s16x8 pa0, pa1, pa2, pa3;
    float ps0, ps1, ps2, ps3;
    SM_GRP(s0, 0, pa0, ps0);
    SM_GRP(s0, 8, pa1, ps1);
    SM_GRP(s1, 0, pa2, ps2);
    SM_GRP(s1, 8, pa3, ps3);
    float sum = (ps0 + ps1) + (ps2 + ps3);
    sum += pair32(sum, hi);
    li += sum;

    o0 = MFMA32(pa0, vfA[0], o0);  o1 = MFMA32(pa0, vfB[0], o1);
    o0 = MFMA32(pa1, vfA[1], o0);  o1 = MFMA32(pa1, vfB[1], o1);
    o0 = MFMA32(pa2, vfA[2], o0);  o1 = MFMA32(pa2, vfB[2], o1);
    o0 = MFMA32(pa3, vfA[3], o0);  o1 = MFMA32(pa3, vfB[3], o1);
  }

  // epilogue: broadcast 1/li per q, scale, store bf16
  if (hi == 0) redL[w][l31] = 1.0f / li;
  f32x4 i0 = *(const f32x4*)&redL[w][hi * 4];
  f32x4 i1 = *(const f32x4*)&redL[w][8 + hi * 4];
  f32x4 i2 = *(const f32x4*)&redL[w][16 + hi * 4];
  f32x4 i3 = *(const f32x4*)&redL[w][24 + hi * 4];

  const int p_glob = (p >> lgHG) * 16 + h0 + (p & ((1 << lgHG) - 1));
  u16* Ab = AO + (size_t)p_glob * 131072 + (size_t)q0 * 64;
#pragma unroll
  for (int g = 0; g < 4; ++g) {
    const f32x4 iv = (g == 0) ? i0 : (g == 1) ? i1 : (g == 2) ? i2 : i3;
#pragma unroll
    for (int e = 0; e < 4; ++e) {
      int row = g * 8 + hi * 4 + e;      // crow(r,hi), r = g*4+e
      Ab[(size_t)row * 64 + l31]      = f2b(o0[g * 4 + e] * iv[e]);
      Ab[(size_t)row * 64 + 32 + l31] = f2b(o1[g * 4 + e] * iv[e]);
    }
  }
}

// k_proj async staging: 3 x global_load_lds(16B) per thread per K-step.
// LDS regions (u16): A @0, b0 @2048, b1 @4096; buffer stride 6144 u16.
#define PISSUE(K, BUF) {                                                     \
    const int c0_ = (K) + scol;                                              \
    GLD16(Abase + (size_t)(c0_ >> 6) * 131072 + (c0_ & 63), (BUF) + w * 512); \
    GLD16(Bg + (K),          (BUF) + 2048 + w * 512);                        \
    GLD16(Bg + 65536 + (K),  (BUF) + 4096 + w * 512);                        \
  }

// ---------------------------------------------------------------------------
// Kernel 3: Out(fp32) = AO @ proj_w^T + proj_b. AO bf16 at [b*16+h][t][64],
// PW bf16 from ws. 64x128 tiles, grid (8,128). LDS dbuf, one barrier/K-step,
// async global_load_lds staging. XCD-grouped swizzle.
// ---------------------------------------------------------------------------
__global__ __launch_bounds__(256, 4) void k_proj(
    const u16* __restrict__ AO, const u16* __restrict__ W,
    const float* __restrict__ Bias, float* __restrict__ Out)
{
  __shared__ __align__(16) u16 smem[12288];   // dbuf 2x(As2048|Bs4096); epi f32 overlay

  const int tid = threadIdx.x;
  const int w = tid >> 6, lane = tid & 63, quad = lane >> 4, l16 = lane & 15;

  // XCD-grouped bijective swizzle (nwg = 1024): 16 M-panels x 8 N per XCD.
  const int hw = blockIdx.y * 8 + blockIdx.x;
  const int lg = (hw & 7) * 128 + (hw >> 3);
  const int m0 = (lg >> 3) * 64, n0 = (lg & 7) * 128;

  const f32x4 z4 = {0.f, 0.f, 0.f, 0.f};
  f32x4 acc[4][2];
#pragma unroll
  for (int i = 0; i < 4; ++i)
#pragma unroll
    for (int j = 0; j < 2; ++j) acc[i][j] = z4;

  const int srow = tid >> 2;                  // 0..63
  const int scol = (tid & 3) * 8;
  const int bb = m0 >> 11, tt = m0 & 2047;    // 64-row tile within one batch
  const u16* Abase = AO + (size_t)bb * 2097152 + (size_t)(tt + srow) * 64;
  const u16* Bg = W + (size_t)(n0 + srow) * 1024 + scol;

  // prologue: async-stage tile 0 into buf 0
  PISSUE(0, smem)

  for (int k0 = 0; k0 < 1024; k0 += 32) {
    u16* Ac = smem + ((k0 >> 5) & 1) * 6144;
    __syncthreads();                       // drains buf[cur] loads; frees other
    if (k0 < 992) {
      u16* An = smem + ((~(k0 >> 5)) & 1) * 6144;
      PISSUE(k0 + 32, An)                  // async, overlaps MFMA below
    }
    s16x8 af[4], bf[2];
#pragma unroll
    for (int i = 0; i < 4; ++i)
      af[i] = *(const s16x8*)&Ac[(i * 16 + l16) * 32 + quad * 8];
#pragma unroll
    for (int j = 0; j < 2; ++j)
      bf[j] = *(const s16x8*)&Ac[2048 + (w * 32 + j * 16 + l16) * 32 + quad * 8];
#pragma unroll
    for (int i = 0; i < 4; ++i)
#pragma unroll
      for (int j = 0; j < 2; ++j)
        acc[i][j] = MFMA16(af[i], bf[j], acc[i][j]);
  }

  const int ncol = n0 + w * 32;
  float bias[2];
#pragma unroll
  for (int j = 0; j < 2; ++j) bias[j] = Bias[ncol + j * 16 + l16];

  __syncthreads();                      // all waves done with staging bufs
  float* OSw = (float*)smem + w * 512;  // per-wave 16 rows x 32 f32 (2 KB)
#pragma unroll
  for (int i = 0; i < 4; ++i) {
#pragma unroll
    for (int j = 0; j < 2; ++j)
#pragma unroll
      for (int r = 0; r < 4; ++r)
        OSw[(quad * 4 + r) * 32 + j * 16 + l16] = acc[i][j][r] + bias[j];
    // same-wave ordering; wide stores: 16B/lane, 128B per 8 lanes
#pragma unroll
    for (int itr = 0; itr < 2; ++itr) {
      int task = itr * 64 + lane;
      int tl = task >> 3, g = task & 7;
      *(f32x4*)&Out[(size_t)(m0 + i * 16 + tl) * 1024 + ncol + g * 4] =
          *(const f32x4*)&OSw[tl * 32 + g * 4];
    }
  }
}

// ---------------------------------------------------------------------------
extern "C" void kernel_launch(void* const* d_in, const int* in_sizes, int n_in,
                              void* d_out, int out_size, void* d_ws, size_t ws_size,
                              hipStream_t stream) {
  const float* X    = (const float*)d_in[0];   // [4,2048,1024] fp32
  const float* QKVW = (const float*)d_in[1];   // [3072,1024]
  const float* QKVB = (const float*)d_in[2];   // [3072]
  const float* PW   = (const float*)d_in[3];   // [1024,1024]
  const float* PB   = (const float*)d_in[4];   // [1024]
  float* Out = (float*)d_out;                  // [4,2048,1024] fp32
  u16* ws = (u16*)d_ws;

  // ws (bytes): HG16: PWOFF+3*segE = 52.4MB (AO aliases Qc);
  // HG<16: + dedicated AO. Fast path: +Xb(16.8MB)+Wb(6.3MB) = 75.5MB.
  int HG, lgHG, ok = 1;
  if      (ws_size >= 52428800ull) { HG = 16; lgHG = 4; }
  else if (ws_size >= 44040192ull) { HG = 8;  lgHG = 3; }
  else if (ws_size >= 31457280ull) { HG = 4;  lgHG = 2; }
  else if (ws_size >= 25165824ull) { HG = 2;  lgHG = 1; }
  else                             { HG = 2;  lgHG = 1; ok = 0; }

  if (!ok) {
    k_beacon<<<dim3(4096), 256, 0, stream>>>(Out, (unsigned long long)ws_size);
    return;
  }

  const size_t segE = 524288ull << lgHG;
  u16* Qc = ws + PWOFF;
  u16* AO = (HG == 16) ? Qc : (Qc + 3 * segE);
  const int lgHB = lgHG + 6;

  // fast path: pre-convert X and QKVW to bf16 (needs 75.5MB total ws)
  const bool fast = (HG == 16) && (ws_size >= 75497472ull);
  u16* Xb = Qc + 3 * segE;                 // 8,388,608 elems
  u16* Wb = Xb + 8388608ull;               // 3,145,728 elems

  k_convert_pw<<<dim3(512), 256, 0, stream>>>(PW, ws);
  if (fast)
    k_convert_xw<<<dim3(5632), 256, 0, stream>>>(X, QKVW, Xb);

  const int chunks = 16 / HG;
  for (int c = 0; c < chunks; ++c) {
    int h0 = c * HG;
    if (fast)
      k_qkv_rope_b<<<dim3((3 * HG) / 2, 64), 256, 0, stream>>>(
          Xb, Wb, QKVB, ws, h0, lgHB, lgHG);
    else
      k_qkv_rope<<<dim3((3 * HG) / 2, 64), 256, 0, stream>>>(
          X, QKVW, QKVB, ws, h0, lgHB, lgHG);
    k_attn<<<dim3(16, 4 * HG), 256, 0, stream>>>(ws, AO, h0, lgHG);
  }
  k_proj<<<dim3(8, 128), 256, 0, stream>>>(AO, ws, PB, Out);
}

// Round 12
// 277.374 us; speedup vs baseline: 1.1056x; 1.1056x over previous
//
#include <hip/hip_runtime.h>

typedef unsigned short u16;
typedef unsigned int   u32;
typedef __attribute__((ext_vector_type(8))) short s16x8;   // 8 x bf16 payload (4 VGPRs)
typedef __attribute__((ext_vector_type(4))) float f32x4;   // MFMA accumulator / f32 quad
typedef __attribute__((ext_vector_type(16))) float f32x16; // 32x32 MFMA accumulator

#define MFMA16(a, b, c) __builtin_amdgcn_mfma_f32_16x16x32_bf16((a), (b), (c), 0, 0, 0)
#define MFMA32(a, b, c) __builtin_amdgcn_mfma_f32_32x32x16_bf16((a), (b), (c), 0, 0, 0)
#define EXP2R(x) __builtin_amdgcn_exp2f(x)   // raw v_exp_f32 (no libm fixup)

// async global->LDS, 16B per lane. LDS dest is wave-uniform base + lane*16.
#define GLD16(gp, lp) __builtin_amdgcn_global_load_lds(                     \
    (const __attribute__((address_space(1))) void*)(gp),                    \
    (__attribute__((address_space(3))) void*)(lp), 16, 0, 0)

// ws layout (bf16 elements): [PW_bf16: 1,048,576][Qc|Kc|Vc: 3*segE][AO if HG<16]
// Fast path (ws >= 75.5MB, HG16): + [Xb: 8,388,608][Wb: 3,145,728] after Vc.
// FRAGMENT-MAJOR layouts (so k_attn hot-loop loads are contiguous 1KB/wave):
//  Qc: [p][qt32 (64)][ks (4)][lane (64)][8]   qt32 = 32-token q tile
//  Kc: [p][kt (32)][ks*2+kb (8)][lane (64)][8]
//  Vc: [p][kt (32)][ks*2+db (8)][lane (64)][8]
#define PWOFF 1048576ull

__device__ __forceinline__ u16 f2b(float f) {
  union { float f; unsigned i; } x; x.f = f;
  unsigned r = x.i + 0x7FFFu + ((x.i >> 16) & 1u);
  return (u16)(r >> 16);
}
__device__ __forceinline__ u32 cvtpk_bf16(float a, float b) {
  u32 r;
  asm("v_cvt_pk_bf16_f32 %0, %1, %2" : "=v"(r) : "v"(a), "v"(b));
  return r;
}
// fp32x8 -> bf16x8 via v_cvt_pk_bf16_f32 (RNE, bit-identical to f2b).
__device__ __forceinline__ s16x8 cvt8(const float* __restrict__ p) {
  f32x4 a = *(const f32x4*)p;
  f32x4 b = *(const f32x4*)(p + 4);
  union { u32 u[4]; s16x8 v; } o;
  o.u[0] = cvtpk_bf16(a[0], a[1]);
  o.u[1] = cvtpk_bf16(a[2], a[3]);
  o.u[2] = cvtpk_bf16(b[0], b[1]);
  o.u[3] = cvtpk_bf16(b[2], b[3]);
  return o.v;
}

__device__ __forceinline__ void plswap(u32& a, u32& b) {
#if __has_builtin(__builtin_amdgcn_permlane32_swap)
  auto r = __builtin_amdgcn_permlane32_swap(a, b, false, false);
  a = r[0]; b = r[1];
#else
  asm volatile("v_permlane32_swap_b32 %0, %1" : "+v"(a), "+v"(b));
#endif
}
// Cross-half (lane <-> lane^32) partner fetch, VALU-only.
__device__ __forceinline__ float pair32(float x, int hi) {
  union { float f; u32 u; } a, b;
  a.f = x; b.f = x;
  plswap(a.u, b.u);
  return hi ? a.f : b.f;
}
// Build PV A-fragment (contraction slice of 16 k) from 8 packed f32 P values.
// Lane holds P[k = crow(r,hi)] with crow = (r&3)+8*(r>>2)+4*hi; the swap gives
// lanes l<->l+32 each other's missing half: frag words (k0k1)(k2k3)(k4k5)(k6k7).
__device__ __forceinline__ s16x8 mk_pa(float e0, float e1, float e2, float e3,
                                       float e4, float e5, float e6, float e7) {
  u32 a0 = cvtpk_bf16(e0, e1), b0 = cvtpk_bf16(e4, e5);
  u32 a1 = cvtpk_bf16(e2, e3), b1 = cvtpk_bf16(e6, e7);
  plswap(a0, b0);
  plswap(a1, b1);
  union { u32 u[4]; s16x8 v; } x;
  x.u[0] = a0; x.u[1] = a1; x.u[2] = b0; x.u[3] = b1;
  return x.v;
}

// exp2 + pack + partial-sum for one group of 8 score elements (streamed: ~8
// live pv floats instead of 32).
#define SM_GRP(sv, ofs, pa_out, ps_out) {                                  \
    float e0 = EXP2R((sv)[(ofs) + 0] * C - mC);                            \
    float e1 = EXP2R((sv)[(ofs) + 1] * C - mC);                            \
    float e2 = EXP2R((sv)[(ofs) + 2] * C - mC);                            \
    float e3 = EXP2R((sv)[(ofs) + 3] * C - mC);                            \
    float e4 = EXP2R((sv)[(ofs) + 4] * C - mC);                            \
    float e5 = EXP2R((sv)[(ofs) + 5] * C - mC);                            \
    float e6 = EXP2R((sv)[(ofs) + 6] * C - mC);                            \
    float e7 = EXP2R((sv)[(ofs) + 7] * C - mC);                            \
    (pa_out) = mk_pa(e0, e1, e2, e3, e4, e5, e6, e7);                      \
    (ps_out) = ((e0 + e1) + (e2 + e3)) + ((e4 + e5) + (e6 + e7));          \
  }

// ---- k_attn per-tile building blocks, parameterized by softmax state ----
// (textually the proven r4 body; only names are parameters)
#define QKT_P(QF, KA, KB, S0, S1) {                                        \
    _Pragma("unroll")                                                      \
    for (int r = 0; r < 16; ++r) { (S0)[r] = 0.f; (S1)[r] = 0.f; }         \
    _Pragma("unroll")                                                      \
    for (int ks = 0; ks < 4; ++ks) {                                       \
      (S0) = MFMA32((KA)[ks], (QF)[ks], (S0));                             \
      (S1) = MFMA32((KB)[ks], (QF)[ks], (S1));                             \
    }                                                                      \
  }

#define SMAX_P(S0, S1, PA0, PA1, PA2, PA3, MR, LI, O0, O1) {               \
    float m8[8];                                                           \
    _Pragma("unroll")                                                      \
    for (int r = 0; r < 8; ++r)                                            \
      m8[r] = fmaxf(fmaxf((S0)[r], (S0)[r + 8]),                           \
                    fmaxf((S1)[r], (S1)[r + 8]));                          \
    float mx = fmaxf(fmaxf(fmaxf(m8[0], m8[1]), fmaxf(m8[2], m8[3])),      \
                     fmaxf(fmaxf(m8[4], m8[5]), fmaxf(m8[6], m8[7])));     \
    mx = fmaxf(mx, pair32(mx, hi));                                        \
    if (!__all(mx - (MR) <= 8.0f)) {                                       \
      float mnew = fmaxf((MR), mx);                                        \
      float al = EXP2R(((MR) - mnew) * C);                                 \
      (MR) = mnew;                                                         \
      (LI) *= al;                                                          \
      if (hi == 0) redL[w][l31] = al;                                      \
      f32x4 a0 = *(const f32x4*)&redL[w][hi * 4];                          \
      f32x4 a1 = *(const f32x4*)&redL[w][8 + hi * 4];                      \
      f32x4 a2 = *(const f32x4*)&redL[w][16 + hi * 4];                     \
      f32x4 a3 = *(const f32x4*)&redL[w][24 + hi * 4];                     \
      _Pragma("unroll")                                                    \
      for (int e = 0; e < 4; ++e) {                                        \
        (O0)[e]      *= a0[e];  (O1)[e]      *= a0[e];                     \
        (O0)[4 + e]  *= a1[e];  (O1)[4 + e]  *= a1[e];                     \
        (O0)[8 + e]  *= a2[e];  (O1)[8 + e]  *= a2[e];                     \
        (O0)[12 + e] *= a3[e];  (O1)[12 + e] *= a3[e];                     \
      }                                                                    \
    }                                                                      \
    const float mC = (MR) * C;                                             \
    float ps0, ps1, ps2, ps3;                                              \
    SM_GRP(S0, 0, PA0, ps0);                                               \
    SM_GRP(S0, 8, PA1, ps1);                                               \
    SM_GRP(S1, 0, PA2, ps2);                                               \
    SM_GRP(S1, 8, PA3, ps3);                                               \
    float sum = (ps0 + ps1) + (ps2 + ps3);                                 \
    sum += pair32(sum, hi);                                                \
    (LI) += sum;                                                           \
  }

#define PV_P(PA0, PA1, PA2, PA3, VA, VB, O0, O1) {                         \
    (O0) = MFMA32((PA0), (VA)[0], (O0));                                   \
    (O1) = MFMA32((PA0), (VB)[0], (O1));                                   \
    (O0) = MFMA32((PA1), (VA)[1], (O0));                                   \
    (O1) = MFMA32((PA1), (VB)[1], (O1));                                   \
    (O0) = MFMA32((PA2), (VA)[2], (O0));                                   \
    (O1) = MFMA32((PA2), (VB)[2], (O1));                                   \
    (O0) = MFMA32((PA3), (VA)[3], (O0));                                   \
    (O1) = MFMA32((PA3), (VB)[3], (O1));                                   \
  }

#define ATT_EPI(LI, O0, O1, Q0) {                                          \
    if (hi == 0) redL[w][l31] = 1.0f / (LI);                               \
    f32x4 i0 = *(const f32x4*)&redL[w][hi * 4];                            \
    f32x4 i1 = *(const f32x4*)&redL[w][8 + hi * 4];                        \
    f32x4 i2 = *(const f32x4*)&redL[w][16 + hi * 4];                       \
    f32x4 i3 = *(const f32x4*)&redL[w][24 + hi * 4];                       \
    u16* Ab = AO + (size_t)p_glob * 131072 + (size_t)(Q0) * 64;            \
    _Pragma("unroll")                                                      \
    for (int g = 0; g < 4; ++g) {                                          \
      const f32x4 iv = (g == 0) ? i0 : (g == 1) ? i1 : (g == 2) ? i2 : i3; \
      _Pragma("unroll")                                                    \
      for (int e = 0; e < 4; ++e) {                                        \
        int row = g * 8 + hi * 4 + e;      /* crow(r,hi), r = g*4+e */     \
        Ab[(size_t)row * 64 + l31]      = f2b((O0)[g * 4 + e] * iv[e]);    \
        Ab[(size_t)row * 64 + 32 + l31] = f2b((O1)[g * 4 + e] * iv[e]);    \
      }                                                                    \
    }                                                                      \
  }

// ---------------------------------------------------------------------------
// Beacon (only if ws too small for any path): fill d_out with 3000+wsMB.
// ---------------------------------------------------------------------------
__global__ void k_beacon(float* __restrict__ Out, unsigned long long ws_size) {
  float V = 3000.0f + fminf((float)(ws_size >> 20), 999.0f);
  size_t i = ((size_t)blockIdx.x * 256 + threadIdx.x) * 8;
#pragma unroll
  for (int j = 0; j < 8; ++j) Out[i + j] = V;
}

// ---------------------------------------------------------------------------
// proj_w fp32 [1024,1024] -> bf16 at ws[0..1048576)
// ---------------------------------------------------------------------------
__global__ void k_convert_pw(const float* __restrict__ PW, u16* __restrict__ ws) {
  size_t i = ((size_t)blockIdx.x * 256 + threadIdx.x) * 8;
  *(s16x8*)(ws + i) = cvt8(PW + i);
}

// ---------------------------------------------------------------------------
// Fast path: X [8192,1024] fp32 and QKVW [3072,1024] fp32 -> bf16 at dst
// (Xb then Wb contiguously). grid 5632 x 256 x 8 elems = 11,534,336.
// ---------------------------------------------------------------------------
__global__ void k_convert_xw(const float* __restrict__ X,
                             const float* __restrict__ W,
                             u16* __restrict__ dst) {
  size_t i = ((size_t)blockIdx.x * 256 + threadIdx.x) * 8;
  const float* src = (i < 8388608ull) ? (X + i) : (W + (i - 8388608ull));
  *(s16x8*)(dst + i) = cvt8(src);
}

// raw f32 loads for one 32-wide K-slice of the qkv GEMM staging (issue-early)
#define QLOAD(K) {                                                 \
    la0 = *(const f32x4*)(Ag + (K));                               \
    la1 = *(const f32x4*)(Ag + (K) + 4);                           \
    lb0 = *(const f32x4*)(Ag + (size_t)64 * 1024 + (K));           \
    lb1 = *(const f32x4*)(Ag + (size_t)64 * 1024 + (K) + 4);       \
    lc0 = *(const f32x4*)(BgA + (K));                              \
    lc1 = *(const f32x4*)(BgA + (K) + 4);                          \
    ld0 = *(const f32x4*)(BgB + (K));                              \
    ld1 = *(const f32x4*)(BgB + (K) + 4);                          \
  }
// convert + LDS-write (write-late: vmcnt waits land here, after the MFMAs)
#define QWRITE(BUF) {                                                         \
    union { u32 u[4]; s16x8 v; } t0, t1, t2, t3;                              \
    t0.u[0] = cvtpk_bf16(la0[0], la0[1]); t0.u[1] = cvtpk_bf16(la0[2], la0[3]); \
    t0.u[2] = cvtpk_bf16(la1[0], la1[1]); t0.u[3] = cvtpk_bf16(la1[2], la1[3]); \
    t1.u[0] = cvtpk_bf16(lb0[0], lb0[1]); t1.u[1] = cvtpk_bf16(lb0[2], lb0[3]); \
    t1.u[2] = cvtpk_bf16(lb1[0], lb1[1]); t1.u[3] = cvtpk_bf16(lb1[2], lb1[3]); \
    t2.u[0] = cvtpk_bf16(lc0[0], lc0[1]); t2.u[1] = cvtpk_bf16(lc0[2], lc0[3]); \
    t2.u[2] = cvtpk_bf16(lc1[0], lc1[1]); t2.u[3] = cvtpk_bf16(lc1[2], lc1[3]); \
    t3.u[0] = cvtpk_bf16(ld0[0], ld0[1]); t3.u[1] = cvtpk_bf16(ld0[2], ld0[3]); \
    t3.u[2] = cvtpk_bf16(ld1[0], ld1[1]); t3.u[3] = cvtpk_bf16(ld1[2], ld1[3]); \
    *(s16x8*)&(BUF)[srow * 32 + scol]               = t0.v;                   \
    *(s16x8*)&(BUF)[(srow + 64) * 32 + scol]        = t1.v;                   \
    *(s16x8*)&(BUF)[4096 + srow * 32 + scol]        = t2.v;                   \
    *(s16x8*)&(BUF)[4096 + (srow + 64) * 32 + scol] = t3.v;                   \
  }

// fast-path async staging: 4 x global_load_lds(16B) per thread per K-step.
#define QISSUEB(K, BUF) {                                          \
    GLD16(Agb + (K),          (BUF) + w * 512);                    \
    GLD16(Agb + 65536 + (K),  (BUF) + 2048 + w * 512);             \
    GLD16(BgAb + (K),         (BUF) + 4096 + w * 512);             \
    GLD16(BgBb + (K),         (BUF) + 6144 + w * 512);             \
  }

// Shared epilogue for both qkv variants (bias + RoPE + fragment-major stores).
#define QKV_EPILOGUE                                                          \
  const int ncol = n0 + wc * 64;              /* 64-aligned (which,hh) */     \
  const int which = ncol >> lgHB;             /* 0=q 1=k 2=v */               \
  const int hh = (ncol & (HB - 1)) >> 6;                                      \
  const int cb = which * 1024 + (h0 + hh) * 64;                               \
  const int mbase = m0 + wr * 64;                                             \
  float bias[4];                                                              \
  _Pragma("unroll")                                                           \
  for (int j = 0; j < 4; ++j) bias[j] = Bias[cb + j * 16 + l16];              \
  __syncthreads();                                                            \
  u16* OSt = smem + w * 4608;                                                 \
  if (which == 2) {                                                           \
    _Pragma("unroll")                                                         \
    for (int i = 0; i < 4; ++i)                                               \
      _Pragma("unroll")                                                       \
      for (int r = 0; r < 4; ++r) {                                           \
        int tl = i * 16 + quad * 4 + r;                                       \
        _Pragma("unroll")                                                     \
        for (int j = 0; j < 4; ++j)                                           \
          OSt[(j * 16 + l16) * 72 + tl] = f2b(acc[i][j][r] + bias[j]);        \
      }                                                                       \
  } else {                                                                    \
    const float LC = 0.1716750968f;                                           \
    float fr0 = exp2f((float)l16 * LC);                                       \
    float fr1 = exp2f((float)(16 + l16) * LC);                                \
    _Pragma("unroll")                                                         \
    for (int i = 0; i < 4; ++i)                                               \
      _Pragma("unroll")                                                       \
      for (int r = 0; r < 4; ++r) {                                           \
        int tl = i * 16 + quad * 4 + r;                                       \
        int tok = mbase + tl;                                                 \
        float ps = (float)(tok & 2047) * (1.0f / 2048.0f);                    \
        float rv0 = ps * fr0; rv0 -= floorf(rv0);                             \
        float rv1 = ps * fr1; rv1 -= floorf(rv1);                             \
        float s0 = __builtin_amdgcn_sinf(rv0), c0 = __builtin_amdgcn_cosf(rv0); \
        float s1 = __builtin_amdgcn_sinf(rv1), c1 = __builtin_amdgcn_cosf(rv1); \
        float x10 = acc[i][0][r] + bias[0], x11 = acc[i][1][r] + bias[1];     \
        float x20 = acc[i][2][r] + bias[2], x21 = acc[i][3][r] + bias[3];     \
        OSt[tl * 72 + l16]      = f2b(x10 * c0 - x20 * s0);                   \
        OSt[tl * 72 + 16 + l16] = f2b(x11 * c1 - x21 * s1);                   \
        OSt[tl * 72 + 32 + l16] = f2b(x10 * s0 + x20 * c0);                   \
        OSt[tl * 72 + 48 + l16] = f2b(x11 * s1 + x21 * c1);                   \
      }                                                                       \
  }                                                                           \
  const int bb = mbase >> 11, tt0 = mbase & 2047;                             \
  const int pp = (bb << lgHG) + hh;                                           \
  if (which == 2) {                                                           \
    u16* D = Vc + ((size_t)pp * 32 + (tt0 >> 6)) * 4096;                      \
    _Pragma("unroll")                                                         \
    for (int fi = 0; fi < 8; ++fi) {                                          \
      int ks = fi >> 1, db = fi & 1;                                          \
      *(s16x8*)&D[fi * 512 + lane * 8] =                                      \
          *(const s16x8*)&OSt[(db * 32 + l31) * 72 + ks * 16 + hi * 8];       \
    }                                                                         \
  } else if (which == 1) {                                                    \
    u16* D = Kc + ((size_t)pp * 32 + (tt0 >> 6)) * 4096;                      \
    _Pragma("unroll")                                                         \
    for (int fi = 0; fi < 8; ++fi) {                                          \
      int ks = fi >> 1, kb = fi & 1;                                          \
      *(s16x8*)&D[fi * 512 + lane * 8] =                                      \
          *(const s16x8*)&OSt[(kb * 32 + l31) * 72 + ks * 16 + hi * 8];       \
    }                                                                         \
  } else {                                                                    \
    u16* D = Qc + ((size_t)pp * 64 + (tt0 >> 5)) * 2048;                      \
    _Pragma("unroll")                                                         \
    for (int fi = 0; fi < 8; ++fi) {                                          \
      int qh = fi >> 2, ks = fi & 3;                                          \
      *(s16x8*)&D[(size_t)qh * 2048 + ks * 512 + lane * 8] =                  \
          *(const s16x8*)&OSt[(qh * 32 + l31) * 72 + ks * 16 + hi * 8];       \
    }                                                                         \
  }

// ---------------------------------------------------------------------------
// Kernel 1 (slow path): fp32 in, cvt in staging. grid ((3*HG)/2, 64), 256 thr.
// ---------------------------------------------------------------------------
__global__ __launch_bounds__(256, 4) void k_qkv_rope(
    const float* __restrict__ X, const float* __restrict__ W,
    const float* __restrict__ Bias, u16* __restrict__ ws,
    int h0, int lgHB, int lgHG)
{
  __shared__ __align__(16) u16 smem[18432];   // dbuf 2x(As4096|Bs4096) | epi 4x(64x72)

  const size_t segE = 524288ull << lgHG;
  u16* Qc = ws + PWOFF;
  u16* Kc = Qc + segE;
  u16* Vc = Kc + segE;

  const int tid = threadIdx.x;
  const int w = tid >> 6, lane = tid & 63, quad = lane >> 4, l16 = lane & 15;
  const int l31 = lane & 31, hi = lane >> 5;
  const int wr = w >> 1, wc = w & 1;
  const int HB = 1 << lgHB;

  const int gx = gridDim.x;
  const int hw = blockIdx.y * gx + blockIdx.x;
  const int cpx = (gx << 6) >> 3;             // nwg/8
  const int lg = (hw & 7) * cpx + (hw >> 3);
  const int m0 = (lg / gx) * 128, n0 = (lg % gx) * 128;

  const f32x4 z4 = {0.f, 0.f, 0.f, 0.f};
  f32x4 acc[4][4];
#pragma unroll
  for (int i = 0; i < 4; ++i)
#pragma unroll
    for (int j = 0; j < 4; ++j) acc[i][j] = z4;

  const int srow = tid >> 2;
  const int scol = (tid & 3) * 8;
  const int nlogA = n0 + srow, nlogB = nlogA + 64;
  const int wrowA = (nlogA >> lgHB) * 1024 + (h0 + ((nlogA & (HB - 1)) >> 6)) * 64 + (nlogA & 63);
  const int wrowB = (nlogB >> lgHB) * 1024 + (h0 + ((nlogB & (HB - 1)) >> 6)) * 64 + (nlogB & 63);
  const float* Ag  = X + (size_t)(m0 + srow) * 1024 + scol;
  const float* BgA = W + (size_t)wrowA * 1024 + scol;
  const float* BgB = W + (size_t)wrowB * 1024 + scol;

  f32x4 la0, la1, lb0, lb1, lc0, lc1, ld0, ld1;
  QLOAD(0)
  QWRITE(smem)

  for (int k0 = 0; k0 < 1024; k0 += 32) {
    u16* Ac = smem + ((k0 >> 5) & 1) * 8192;
    if (k0 < 992) QLOAD(k0 + 32)          // issue-early
    __syncthreads();                       // buf[cur] visible; buf[cur^1] free
    s16x8 af[4], bf[4];
#pragma unroll
    for (int i = 0; i < 4; ++i)
      af[i] = *(const s16x8*)&Ac[(wr * 64 + i * 16 + l16) * 32 + quad * 8];
#pragma unroll
    for (int j = 0; j < 4; ++j)
      bf[j] = *(const s16x8*)&Ac[4096 + (wc * 64 + j * 16 + l16) * 32 + quad * 8];
#pragma unroll
    for (int i = 0; i < 4; ++i)
#pragma unroll
      for (int j = 0; j < 4; ++j)
        acc[i][j] = MFMA16(af[i], bf[j], acc[i][j]);
    if (k0 < 992) {
      u16* An = smem + ((~(k0 >> 5)) & 1) * 8192;
      QWRITE(An)                           // cvt+write late
    }
  }

  QKV_EPILOGUE
}

// ---------------------------------------------------------------------------
// Kernel 1b (fast path): bf16 X/W pre-converted -> async global_load_lds
// staging (m97 pattern).
// ---------------------------------------------------------------------------
__global__ __launch_bounds__(256, 4) void k_qkv_rope_b(
    const u16* __restrict__ Xb, const u16* __restrict__ Wb,
    const float* __restrict__ Bias, u16* __restrict__ ws,
    int h0, int lgHB, int lgHG)
{
  __shared__ __align__(16) u16 smem[18432];   // dbuf 2x(As4096|Bs4096) | epi 4x(64x72)

  const size_t segE = 524288ull << lgHG;
  u16* Qc = ws + PWOFF;
  u16* Kc = Qc + segE;
  u16* Vc = Kc + segE;

  const int tid = threadIdx.x;
  const int w = tid >> 6, lane = tid & 63, quad = lane >> 4, l16 = lane & 15;
  const int l31 = lane & 31, hi = lane >> 5;
  const int wr = w >> 1, wc = w & 1;
  const int HB = 1 << lgHB;

  const int gx = gridDim.x;
  const int hw = blockIdx.y * gx + blockIdx.x;
  const int cpx = (gx << 6) >> 3;             // nwg/8
  const int lg = (hw & 7) * cpx + (hw >> 3);
  const int m0 = (lg / gx) * 128, n0 = (lg % gx) * 128;

  const f32x4 z4 = {0.f, 0.f, 0.f, 0.f};
  f32x4 acc[4][4];
#pragma unroll
  for (int i = 0; i < 4; ++i)
#pragma unroll
    for (int j = 0; j < 4; ++j) acc[i][j] = z4;

  const int srow = tid >> 2;
  const int scol = (tid & 3) * 8;
  const int nlogA = n0 + srow, nlogB = nlogA + 64;
  const int wrowA = (nlogA >> lgHB) * 1024 + (h0 + ((nlogA & (HB - 1)) >> 6)) * 64 + (nlogA & 63);
  const int wrowB = (nlogB >> lgHB) * 1024 + (h0 + ((nlogB & (HB - 1)) >> 6)) * 64 + (nlogB & 63);
  const u16* Agb  = Xb + (size_t)(m0 + srow) * 1024 + scol;
  const u16* BgAb = Wb + (size_t)wrowA * 1024 + scol;
  const u16* BgBb = Wb + (size_t)wrowB * 1024 + scol;

  // prologue: async-stage tile 0 into buf 0
  QISSUEB(0, smem)

  for (int k0 = 0; k0 < 1024; k0 += 32) {
    u16* Ac = smem + ((k0 >> 5) & 1) * 8192;
    __syncthreads();                       // drains buf[cur] loads; frees other
    if (k0 < 992) {
      u16* An = smem + ((~(k0 >> 5)) & 1) * 8192;
      QISSUEB(k0 + 32, An)                 // async, overlaps MFMA below
    }
    s16x8 af[4], bf[4];
#pragma unroll
    for (int i = 0; i < 4; ++i)
      af[i] = *(const s16x8*)&Ac[(wr * 64 + i * 16 + l16) * 32 + quad * 8];
#pragma unroll
    for (int j = 0; j < 4; ++j)
      bf[j] = *(const s16x8*)&Ac[4096 + (wc * 64 + j * 16 + l16) * 32 + quad * 8];
#pragma unroll
    for (int i = 0; i < 4; ++i)
#pragma unroll
      for (int j = 0; j < 4; ++j)
        acc[i][j] = MFMA16(af[i], bf[j], acc[i][j]);
  }

  QKV_EPILOGUE
}

// ---------------------------------------------------------------------------
// Kernel 2: flash attention, r12: TWO softmax states per wave (64 q-rows:
// A = [q0, q0+32), B = [q0+128, q0+160)) sharing ONE K/V fragment load per
// tile -> TA bytes per q-row halved (TA was ~85% busy, the binding pipe).
// Per-state math is the byte-level r4 body (QKT_P/SMAX_P/PV_P). Load
// placement unchanged from r4. grid (8, 4*HG), 256 thr, launch_bounds(256,2)
// (peak live ~240 regs; 2 blocks/CU x 4 waves = 8 waves/CU consistent).
// ---------------------------------------------------------------------------
__global__ __launch_bounds__(256, 2) void k_attn(
    u16* __restrict__ ws, u16* __restrict__ AO, int h0, int lgHG)
{
  __shared__ float redL[4][32];          // per-wave alpha / inv-li broadcast

  const size_t segE = 524288ull << lgHG;
  const u16* Qg = ws + PWOFF;
  const u16* Kg = Qg + segE;
  const u16* Vg = Kg + segE;

  const int tid = threadIdx.x;
  const int w = tid >> 6, lane = tid & 63;
  const int l31 = lane & 31, hi = lane >> 5;

  // XCD swizzle: n = by*8 + bx; xcd = n&7 gets heads [xcd*P/8, ...)
  const int P = 4 << lgHG;
  const int n = blockIdx.y * 8 + blockIdx.x;
  const int mm = n >> 3;
  const int p  = (n & 7) * (P >> 3) + (mm >> 3);
  const int qt = mm & 7;                 // 256-row q tile

  const u16* Kb = Kg + (size_t)p * 131072;
  const u16* Vb = Vg + (size_t)p * 131072;
  const int q0A = qt * 256 + w * 32;
  const int q0B = q0A + 128;

  // Q fragments: frag-major; qt32 = q0/32
  const u16* QtA = Qg + (size_t)p * 131072 + (size_t)(qt * 8 + w) * 2048;
  const u16* QtB = QtA + 4 * 2048;
  s16x8 qfA[4], qfB[4];
#pragma unroll
  for (int ks = 0; ks < 4; ++ks) {
    qfA[ks] = *(const s16x8*)&QtA[ks * 512 + lane * 8];
    qfB[ks] = *(const s16x8*)&QtB[ks * 512 + lane * 8];
  }

  f32x16 oA0, oA1, oB0, oB1;             // O[q=crow(r,hi)][d=l31 (+32)]
#pragma unroll
  for (int r = 0; r < 16; ++r) { oA0[r] = 0.f; oA1[r] = 0.f; oB0[r] = 0.f; oB1[r] = 0.f; }
  float mA = -1e30f, lA = 0.f, mB = -1e30f, lB = 0.f;
  const float C = 0.1803368801f;         // 0.125 * log2(e)

  for (int kt = 0; kt < 32; ++kt) {
    const u16* Kt = Kb + (size_t)kt * 4096;
    const u16* Vt = Vb + (size_t)kt * 4096;
    s16x8 kfA[4], kfB[4], vfA[4], vfB[4];
#pragma unroll
    for (int ks = 0; ks < 4; ++ks) {
      kfA[ks] = *(const s16x8*)&Kt[(ks * 2 + 0) * 512 + lane * 8];
      kfB[ks] = *(const s16x8*)&Kt[(ks * 2 + 1) * 512 + lane * 8];
    }
#pragma unroll
    for (int ks = 0; ks < 4; ++ks) {
      vfA[ks] = *(const s16x8*)&Vt[(ks * 2 + 0) * 512 + lane * 8];
      vfB[ks] = *(const s16x8*)&Vt[(ks * 2 + 1) * 512 + lane * 8];
    }

    // both QK^T first (kf dies early; 16 back-to-back MFMAs)
    f32x16 sA0, sA1, sB0, sB1;
    QKT_P(qfA, kfA, kfB, sA0, sA1)
    QKT_P(qfB, kfA, kfB, sB0, sB1)

    {
      s16x8 pa0, pa1, pa2, pa3;
      SMAX_P(sA0, sA1, pa0, pa1, pa2, pa3, mA, lA, oA0, oA1)
      PV_P(pa0, pa1, pa2, pa3, vfA, vfB, oA0, oA1)
    }
    {
      s16x8 pa0, pa1, pa2, pa3;
      SMAX_P(sB0, sB1, pa0, pa1, pa2, pa3, mB, lB, oB0, oB1)
      PV_P(pa0, pa1, pa2, pa3, vfA, vfB, oB0, oB1)
    }
  }

  const int p_glob = (p >> lgHG) * 16 + h0 + (p & ((1 << lgHG) - 1));
  ATT_EPI(lA, oA0, oA1, q0A)
  ATT_EPI(lB, oB0, oB1, q0B)
}

// k_proj async staging: 3 x global_load_lds(16B) per thread per K-step.
#define PISSUE(K, BUF) {                                                     \
    const int c0_ = (K) + scol;                                              \
    GLD16(Abase + (size_t)(c0_ >> 6) * 131072 + (c0_ & 63), (BUF) + w * 512); \
    GLD16(Bg + (K),          (BUF) + 2048 + w * 512);                        \
    GLD16(Bg + 65536 + (K),  (BUF) + 4096 + w * 512);                        \
  }

// ---------------------------------------------------------------------------
// Kernel 3: Out(fp32) = AO @ proj_w^T + proj_b. 64x128 tiles, grid (8,128).
// LDS dbuf, one barrier/K-step, async global_load_lds staging. XCD swizzle.
// ---------------------------------------------------------------------------
__global__ __launch_bounds__(256, 4) void k_proj(
    const u16* __restrict__ AO, const u16* __restrict__ W,
    const float* __restrict__ Bias, float* __restrict__ Out)
{
  __shared__ __align__(16) u16 smem[12288];   // dbuf 2x(As2048|Bs4096); epi f32 overlay

  const int tid = threadIdx.x;
  const int w = tid >> 6, lane = tid & 63, quad = lane >> 4, l16 = lane & 15;

  // XCD-grouped bijective swizzle (nwg = 1024): 16 M-panels x 8 N per XCD.
  const int hw = blockIdx.y * 8 + blockIdx.x;
  const int lg = (hw & 7) * 128 + (hw >> 3);
  const int m0 = (lg >> 3) * 64, n0 = (lg & 7) * 128;

  const f32x4 z4 = {0.f, 0.f, 0.f, 0.f};
  f32x4 acc[4][2];
#pragma unroll
  for (int i = 0; i < 4; ++i)
#pragma unroll
    for (int j = 0; j < 2; ++j) acc[i][j] = z4;

  const int srow = tid >> 2;                  // 0..63
  const int scol = (tid & 3) * 8;
  const int bb = m0 >> 11, tt = m0 & 2047;    // 64-row tile within one batch
  const u16* Abase = AO + (size_t)bb * 2097152 + (size_t)(tt + srow) * 64;
  const u16* Bg = W + (size_t)(n0 + srow) * 1024 + scol;

  // prologue: async-stage tile 0 into buf 0
  PISSUE(0, smem)

  for (int k0 = 0; k0 < 1024; k0 += 32) {
    u16* Ac = smem + ((k0 >> 5) & 1) * 6144;
    __syncthreads();                       // drains buf[cur] loads; frees other
    if (k0 < 992) {
      u16* An = smem + ((~(k0 >> 5)) & 1) * 6144;
      PISSUE(k0 + 32, An)                  // async, overlaps MFMA below
    }
    s16x8 af[4], bf[2];
#pragma unroll
    for (int i = 0; i < 4; ++i)
      af[i] = *(const s16x8*)&Ac[(i * 16 + l16) * 32 + quad * 8];
#pragma unroll
    for (int j = 0; j < 2; ++j)
      bf[j] = *(const s16x8*)&Ac[2048 + (w * 32 + j * 16 + l16) * 32 + quad * 8];
#pragma unroll
    for (int i = 0; i < 4; ++i)
#pragma unroll
      for (int j = 0; j < 2; ++j)
        acc[i][j] = MFMA16(af[i], bf[j], acc[i][j]);
  }

  const int ncol = n0 + w * 32;
  float bias[2];
#pragma unroll
  for (int j = 0; j < 2; ++j) bias[j] = Bias[ncol + j * 16 + l16];

  __syncthreads();                      // all waves done with staging bufs
  float* OSw = (float*)smem + w * 512;  // per-wave 16 rows x 32 f32 (2 KB)
#pragma unroll
  for (int i = 0; i < 4; ++i) {
#pragma unroll
    for (int j = 0; j < 2; ++j)
#pragma unroll
      for (int r = 0; r < 4; ++r)
        OSw[(quad * 4 + r) * 32 + j * 16 + l16] = acc[i][j][r] + bias[j];
    // same-wave ordering; wide stores: 16B/lane, 128B per 8 lanes
#pragma unroll
    for (int itr = 0; itr < 2; ++itr) {
      int task = itr * 64 + lane;
      int tl = task >> 3, g = task & 7;
      *(f32x4*)&Out[(size_t)(m0 + i * 16 + tl) * 1024 + ncol + g * 4] =
          *(const f32x4*)&OSw[tl * 32 + g * 4];
    }
  }
}

// ---------------------------------------------------------------------------
extern "C" void kernel_launch(void* const* d_in, const int* in_sizes, int n_in,
                              void* d_out, int out_size, void* d_ws, size_t ws_size,
                              hipStream_t stream) {
  const float* X    = (const float*)d_in[0];   // [4,2048,1024] fp32
  const float* QKVW = (const float*)d_in[1];   // [3072,1024]
  const float* QKVB = (const float*)d_in[2];   // [3072]
  const float* PW   = (const float*)d_in[3];   // [1024,1024]
  const float* PB   = (const float*)d_in[4];   // [1024]
  float* Out = (float*)d_out;                  // [4,2048,1024] fp32
  u16* ws = (u16*)d_ws;

  // ws (bytes): HG16: PWOFF+3*segE = 52.4MB (AO aliases Qc);
  // HG<16: + dedicated AO. Fast path: +Xb(16.8MB)+Wb(6.3MB) = 75.5MB.
  int HG, lgHG, ok = 1;
  if      (ws_size >= 52428800ull) { HG = 16; lgHG = 4; }
  else if (ws_size >= 44040192ull) { HG = 8;  lgHG = 3; }
  else if (ws_size >= 31457280ull) { HG = 4;  lgHG = 2; }
  else if (ws_size >= 25165824ull) { HG = 2;  lgHG = 1; }
  else                             { HG = 2;  lgHG = 1; ok = 0; }

  if (!ok) {
    k_beacon<<<dim3(4096), 256, 0, stream>>>(Out, (unsigned long long)ws_size);
    return;
  }

  const size_t segE = 524288ull << lgHG;
  u16* Qc = ws + PWOFF;
  u16* AO = (HG == 16) ? Qc : (Qc + 3 * segE);
  const int lgHB = lgHG + 6;

  // fast path: pre-convert X and QKVW to bf16 (needs 75.5MB total ws)
  const bool fast = (HG == 16) && (ws_size >= 75497472ull);
  u16* Xb = Qc + 3 * segE;                 // 8,388,608 elems
  u16* Wb = Xb + 8388608ull;               // 3,145,728 elems

  k_convert_pw<<<dim3(512), 256, 0, stream>>>(PW, ws);
  if (fast)
    k_convert_xw<<<dim3(5632), 256, 0, stream>>>(X, QKVW, Xb);

  const int chunks = 16 / HG;
  for (int c = 0; c < chunks; ++c) {
    int h0 = c * HG;
    if (fast)
      k_qkv_rope_b<<<dim3((3 * HG) / 2, 64), 256, 0, stream>>>(
          Xb, Wb, QKVB, ws, h0, lgHB, lgHG);
    else
      k_qkv_rope<<<dim3((3 * HG) / 2, 64), 256, 0, stream>>>(
          X, QKVW, QKVB, ws, h0, lgHB, lgHG);
    k_attn<<<dim3(8, 4 * HG), 256, 0, stream>>>(ws, AO, h0, lgHG);
  }
  k_proj<<<dim3(8, 128), 256, 0, stream>>>(AO, ws, PB, Out);
}

// Round 13
// 274.792 us; speedup vs baseline: 1.1160x; 1.0094x over previous
//
#include <hip/hip_runtime.h>

typedef unsigned short u16;
typedef unsigned int   u32;
typedef __attribute__((ext_vector_type(8))) short s16x8;   // 8 x bf16 payload (4 VGPRs)
typedef __attribute__((ext_vector_type(4))) float f32x4;   // MFMA accumulator / f32 quad
typedef __attribute__((ext_vector_type(16))) float f32x16; // 32x32 MFMA accumulator

#define MFMA16(a, b, c) __builtin_amdgcn_mfma_f32_16x16x32_bf16((a), (b), (c), 0, 0, 0)
#define MFMA32(a, b, c) __builtin_amdgcn_mfma_f32_32x32x16_bf16((a), (b), (c), 0, 0, 0)
#define EXP2R(x) __builtin_amdgcn_exp2f(x)   // raw v_exp_f32 (no libm fixup)

// async global->LDS, 16B per lane. LDS dest is wave-uniform base + lane*16.
#define GLD16(gp, lp) __builtin_amdgcn_global_load_lds(                     \
    (const __attribute__((address_space(1))) void*)(gp),                    \
    (__attribute__((address_space(3))) void*)(lp), 16, 0, 0)

// ws layout (bf16 elements): [PW_bf16: 1,048,576][Qc|Kc|Vc: 3*segE][AO if HG<16]
// Fast path (ws >= 75.5MB, HG16): + [Xb: 8,388,608][Wb: 3,145,728] after Vc.
// FRAGMENT-MAJOR layouts (so k_attn hot-loop loads are contiguous 1KB/wave):
//  Qc: [p][qt32 (64)][ks (4)][lane (64)][8]   qt32 = 32-token q tile
//  Kc: [p][kt (32)][ks*2+kb (8)][lane (64)][8]
//  Vc: [p][kt (32)][ks*2+db (8)][lane (64)][8]
#define PWOFF 1048576ull

__device__ __forceinline__ u16 f2b(float f) {
  union { float f; unsigned i; } x; x.f = f;
  unsigned r = x.i + 0x7FFFu + ((x.i >> 16) & 1u);
  return (u16)(r >> 16);
}
__device__ __forceinline__ u32 cvtpk_bf16(float a, float b) {
  u32 r;
  asm("v_cvt_pk_bf16_f32 %0, %1, %2" : "=v"(r) : "v"(a), "v"(b));
  return r;
}
// fp32x8 -> bf16x8 via v_cvt_pk_bf16_f32 (RNE, bit-identical to f2b).
__device__ __forceinline__ s16x8 cvt8(const float* __restrict__ p) {
  f32x4 a = *(const f32x4*)p;
  f32x4 b = *(const f32x4*)(p + 4);
  union { u32 u[4]; s16x8 v; } o;
  o.u[0] = cvtpk_bf16(a[0], a[1]);
  o.u[1] = cvtpk_bf16(a[2], a[3]);
  o.u[2] = cvtpk_bf16(b[0], b[1]);
  o.u[3] = cvtpk_bf16(b[2], b[3]);
  return o.v;
}

__device__ __forceinline__ void plswap(u32& a, u32& b) {
#if __has_builtin(__builtin_amdgcn_permlane32_swap)
  auto r = __builtin_amdgcn_permlane32_swap(a, b, false, false);
  a = r[0]; b = r[1];
#else
  asm volatile("v_permlane32_swap_b32 %0, %1" : "+v"(a), "+v"(b));
#endif
}
// Cross-half (lane <-> lane^32) partner fetch, VALU-only.
__device__ __forceinline__ float pair32(float x, int hi) {
  union { float f; u32 u; } a, b;
  a.f = x; b.f = x;
  plswap(a.u, b.u);
  return hi ? a.f : b.f;
}
// Build PV A-fragment (contraction slice of 16 k) from 8 packed f32 P values.
// Lane holds P[k = crow(r,hi)] with crow = (r&3)+8*(r>>2)+4*hi; the swap gives
// lanes l<->l+32 each other's missing half: frag words (k0k1)(k2k3)(k4k5)(k6k7).
__device__ __forceinline__ s16x8 mk_pa(float e0, float e1, float e2, float e3,
                                       float e4, float e5, float e6, float e7) {
  u32 a0 = cvtpk_bf16(e0, e1), b0 = cvtpk_bf16(e4, e5);
  u32 a1 = cvtpk_bf16(e2, e3), b1 = cvtpk_bf16(e6, e7);
  plswap(a0, b0);
  plswap(a1, b1);
  union { u32 u[4]; s16x8 v; } x;
  x.u[0] = a0; x.u[1] = a1; x.u[2] = b0; x.u[3] = b1;
  return x.v;
}

// exp2 + pack + partial-sum for one group of 8 score elements (streamed: ~8
// live pv floats instead of 32).
#define SM_GRP(sv, ofs, pa_out, ps_out) {                                  \
    float e0 = EXP2R((sv)[(ofs) + 0] * C - mC);                            \
    float e1 = EXP2R((sv)[(ofs) + 1] * C - mC);                            \
    float e2 = EXP2R((sv)[(ofs) + 2] * C - mC);                            \
    float e3 = EXP2R((sv)[(ofs) + 3] * C - mC);                            \
    float e4 = EXP2R((sv)[(ofs) + 4] * C - mC);                            \
    float e5 = EXP2R((sv)[(ofs) + 5] * C - mC);                            \
    float e6 = EXP2R((sv)[(ofs) + 6] * C - mC);                            \
    float e7 = EXP2R((sv)[(ofs) + 7] * C - mC);                            \
    (pa_out) = mk_pa(e0, e1, e2, e3, e4, e5, e6, e7);                      \
    (ps_out) = ((e0 + e1) + (e2 + e3)) + ((e4 + e5) + (e6 + e7));          \
  }

// ---- k_attn per-tile building blocks, parameterized by softmax state ----
#define QKT_P(QF, KA, KB, S0, S1) {                                        \
    _Pragma("unroll")                                                      \
    for (int r = 0; r < 16; ++r) { (S0)[r] = 0.f; (S1)[r] = 0.f; }         \
    _Pragma("unroll")                                                      \
    for (int ks = 0; ks < 4; ++ks) {                                       \
      (S0) = MFMA32((KA)[ks], (QF)[ks], (S0));                             \
      (S1) = MFMA32((KB)[ks], (QF)[ks], (S1));                             \
    }                                                                      \
  }

#define SMAX_P(S0, S1, PA0, PA1, PA2, PA3, MR, LI, O0, O1) {               \
    float m8[8];                                                           \
    _Pragma("unroll")                                                      \
    for (int r = 0; r < 8; ++r)                                            \
      m8[r] = fmaxf(fmaxf((S0)[r], (S0)[r + 8]),                           \
                    fmaxf((S1)[r], (S1)[r + 8]));                          \
    float mx = fmaxf(fmaxf(fmaxf(m8[0], m8[1]), fmaxf(m8[2], m8[3])),      \
                     fmaxf(fmaxf(m8[4], m8[5]), fmaxf(m8[6], m8[7])));     \
    mx = fmaxf(mx, pair32(mx, hi));                                        \
    if (!__all(mx - (MR) <= 8.0f)) {                                       \
      float mnew = fmaxf((MR), mx);                                        \
      float al = EXP2R(((MR) - mnew) * C);                                 \
      (MR) = mnew;                                                         \
      (LI) *= al;                                                          \
      if (hi == 0) redL[w][l31] = al;                                      \
      f32x4 a0 = *(const f32x4*)&redL[w][hi * 4];                          \
      f32x4 a1 = *(const f32x4*)&redL[w][8 + hi * 4];                      \
      f32x4 a2 = *(const f32x4*)&redL[w][16 + hi * 4];                     \
      f32x4 a3 = *(const f32x4*)&redL[w][24 + hi * 4];                     \
      _Pragma("unroll")                                                    \
      for (int e = 0; e < 4; ++e) {                                        \
        (O0)[e]      *= a0[e];  (O1)[e]      *= a0[e];                     \
        (O0)[4 + e]  *= a1[e];  (O1)[4 + e]  *= a1[e];                     \
        (O0)[8 + e]  *= a2[e];  (O1)[8 + e]  *= a2[e];                     \
        (O0)[12 + e] *= a3[e];  (O1)[12 + e] *= a3[e];                     \
      }                                                                    \
    }                                                                      \
    const float mC = (MR) * C;                                             \
    float ps0, ps1, ps2, ps3;                                              \
    SM_GRP(S0, 0, PA0, ps0);                                               \
    SM_GRP(S0, 8, PA1, ps1);                                               \
    SM_GRP(S1, 0, PA2, ps2);                                               \
    SM_GRP(S1, 8, PA3, ps3);                                               \
    float sum = (ps0 + ps1) + (ps2 + ps3);                                 \
    sum += pair32(sum, hi);                                                \
    (LI) += sum;                                                           \
  }

#define PV_P(PA0, PA1, PA2, PA3, VA, VB, O0, O1) {                         \
    (O0) = MFMA32((PA0), (VA)[0], (O0));                                   \
    (O1) = MFMA32((PA0), (VB)[0], (O1));                                   \
    (O0) = MFMA32((PA1), (VA)[1], (O0));                                   \
    (O1) = MFMA32((PA1), (VB)[1], (O1));                                   \
    (O0) = MFMA32((PA2), (VA)[2], (O0));                                   \
    (O1) = MFMA32((PA2), (VB)[2], (O1));                                   \
    (O0) = MFMA32((PA3), (VA)[3], (O0));                                   \
    (O1) = MFMA32((PA3), (VB)[3], (O1));                                   \
  }

#define ATT_EPI(LI, O0, O1, Q0) {                                          \
    if (hi == 0) redL[w][l31] = 1.0f / (LI);                               \
    f32x4 i0 = *(const f32x4*)&redL[w][hi * 4];                            \
    f32x4 i1 = *(const f32x4*)&redL[w][8 + hi * 4];                        \
    f32x4 i2 = *(const f32x4*)&redL[w][16 + hi * 4];                       \
    f32x4 i3 = *(const f32x4*)&redL[w][24 + hi * 4];                       \
    u16* Ab = AO + (size_t)p_glob * 131072 + (size_t)(Q0) * 64;            \
    _Pragma("unroll")                                                      \
    for (int g = 0; g < 4; ++g) {                                          \
      const f32x4 iv = (g == 0) ? i0 : (g == 1) ? i1 : (g == 2) ? i2 : i3; \
      _Pragma("unroll")                                                    \
      for (int e = 0; e < 4; ++e) {                                        \
        int row = g * 8 + hi * 4 + e;      /* crow(r,hi), r = g*4+e */     \
        Ab[(size_t)row * 64 + l31]      = f2b((O0)[g * 4 + e] * iv[e]);    \
        Ab[(size_t)row * 64 + 32 + l31] = f2b((O1)[g * 4 + e] * iv[e]);    \
      }                                                                    \
    }                                                                      \
  }

// ---------------------------------------------------------------------------
// Beacon (only if ws too small for any path): fill d_out with 3000+wsMB.
// ---------------------------------------------------------------------------
__global__ void k_beacon(float* __restrict__ Out, unsigned long long ws_size) {
  float V = 3000.0f + fminf((float)(ws_size >> 20), 999.0f);
  size_t i = ((size_t)blockIdx.x * 256 + threadIdx.x) * 8;
#pragma unroll
  for (int j = 0; j < 8; ++j) Out[i + j] = V;
}

// ---------------------------------------------------------------------------
// proj_w fp32 [1024,1024] -> bf16 at ws[0..1048576)   (slow path only)
// ---------------------------------------------------------------------------
__global__ void k_convert_pw(const float* __restrict__ PW, u16* __restrict__ ws) {
  size_t i = ((size_t)blockIdx.x * 256 + threadIdx.x) * 8;
  *(s16x8*)(ws + i) = cvt8(PW + i);
}

// ---------------------------------------------------------------------------
// Fast path: single launch converts PW -> ws[0], X -> Xb, QKVW -> Wb.
// total elems = 1,048,576 + 8,388,608 + 3,145,728 = 12,582,912; grid 6144.
// ---------------------------------------------------------------------------
__global__ void k_convert_all(const float* __restrict__ PW,
                              const float* __restrict__ X,
                              const float* __restrict__ W,
                              u16* __restrict__ ws, u16* __restrict__ Xb) {
  size_t i = ((size_t)blockIdx.x * 256 + threadIdx.x) * 8;
  if (i < 1048576ull) {
    *(s16x8*)(ws + i) = cvt8(PW + i);
  } else {
    size_t j = i - 1048576ull;
    const float* src = (j < 8388608ull) ? (X + j) : (W + (j - 8388608ull));
    *(s16x8*)(Xb + j) = cvt8(src);
  }
}

// raw f32 loads for one 32-wide K-slice of the qkv GEMM staging (issue-early)
#define QLOAD(K) {                                                 \
    la0 = *(const f32x4*)(Ag + (K));                               \
    la1 = *(const f32x4*)(Ag + (K) + 4);                           \
    lb0 = *(const f32x4*)(Ag + (size_t)64 * 1024 + (K));           \
    lb1 = *(const f32x4*)(Ag + (size_t)64 * 1024 + (K) + 4);       \
    lc0 = *(const f32x4*)(BgA + (K));                              \
    lc1 = *(const f32x4*)(BgA + (K) + 4);                          \
    ld0 = *(const f32x4*)(BgB + (K));                              \
    ld1 = *(const f32x4*)(BgB + (K) + 4);                          \
  }
// convert + LDS-write (write-late: vmcnt waits land here, after the MFMAs)
#define QWRITE(BUF) {                                                         \
    union { u32 u[4]; s16x8 v; } t0, t1, t2, t3;                              \
    t0.u[0] = cvtpk_bf16(la0[0], la0[1]); t0.u[1] = cvtpk_bf16(la0[2], la0[3]); \
    t0.u[2] = cvtpk_bf16(la1[0], la1[1]); t0.u[3] = cvtpk_bf16(la1[2], la1[3]); \
    t1.u[0] = cvtpk_bf16(lb0[0], lb0[1]); t1.u[1] = cvtpk_bf16(lb0[2], lb0[3]); \
    t1.u[2] = cvtpk_bf16(lb1[0], lb1[1]); t1.u[3] = cvtpk_bf16(lb1[2], lb1[3]); \
    t2.u[0] = cvtpk_bf16(lc0[0], lc0[1]); t2.u[1] = cvtpk_bf16(lc0[2], lc0[3]); \
    t2.u[2] = cvtpk_bf16(lc1[0], lc1[1]); t2.u[3] = cvtpk_bf16(lc1[2], lc1[3]); \
    t3.u[0] = cvtpk_bf16(ld0[0], ld0[1]); t3.u[1] = cvtpk_bf16(ld0[2], ld0[3]); \
    t3.u[2] = cvtpk_bf16(ld1[0], ld1[1]); t3.u[3] = cvtpk_bf16(ld1[2], ld1[3]); \
    *(s16x8*)&(BUF)[srow * 32 + scol]               = t0.v;                   \
    *(s16x8*)&(BUF)[(srow + 64) * 32 + scol]        = t1.v;                   \
    *(s16x8*)&(BUF)[4096 + srow * 32 + scol]        = t2.v;                   \
    *(s16x8*)&(BUF)[4096 + (srow + 64) * 32 + scol] = t3.v;                   \
  }

// fast-path async staging: 4 x global_load_lds(16B) per thread per K-step.
#define QISSUEB(K, BUF) {                                          \
    GLD16(Agb + (K),          (BUF) + w * 512);                    \
    GLD16(Agb + 65536 + (K),  (BUF) + 2048 + w * 512);             \
    GLD16(BgAb + (K),         (BUF) + 4096 + w * 512);             \
    GLD16(BgBb + (K),         (BUF) + 6144 + w * 512);             \
  }

// Shared epilogue for both qkv variants (bias + RoPE + fragment-major stores).
#define QKV_EPILOGUE                                                          \
  const int ncol = n0 + wc * 64;              /* 64-aligned (which,hh) */     \
  const int which = ncol >> lgHB;             /* 0=q 1=k 2=v */               \
  const int hh = (ncol & (HB - 1)) >> 6;                                      \
  const int cb = which * 1024 + (h0 + hh) * 64;                               \
  const int mbase = m0 + wr * 64;                                             \
  float bias[4];                                                              \
  _Pragma("unroll")                                                           \
  for (int j = 0; j < 4; ++j) bias[j] = Bias[cb + j * 16 + l16];              \
  __syncthreads();                                                            \
  u16* OSt = smem + w * 4608;                                                 \
  if (which == 2) {                                                           \
    _Pragma("unroll")                                                         \
    for (int i = 0; i < 4; ++i)                                               \
      _Pragma("unroll")                                                       \
      for (int r = 0; r < 4; ++r) {                                           \
        int tl = i * 16 + quad * 4 + r;                                       \
        _Pragma("unroll")                                                     \
        for (int j = 0; j < 4; ++j)                                           \
          OSt[(j * 16 + l16) * 72 + tl] = f2b(acc[i][j][r] + bias[j]);        \
      }                                                                       \
  } else {                                                                    \
    const float LC = 0.1716750968f;                                           \
    float fr0 = exp2f((float)l16 * LC);                                       \
    float fr1 = exp2f((float)(16 + l16) * LC);                                \
    _Pragma("unroll")                                                         \
    for (int i = 0; i < 4; ++i)                                               \
      _Pragma("unroll")                                                       \
      for (int r = 0; r < 4; ++r) {                                           \
        int tl = i * 16 + quad * 4 + r;                                       \
        int tok = mbase + tl;                                                 \
        float ps = (float)(tok & 2047) * (1.0f / 2048.0f);                    \
        float rv0 = ps * fr0; rv0 -= floorf(rv0);                             \
        float rv1 = ps * fr1; rv1 -= floorf(rv1);                             \
        float s0 = __builtin_amdgcn_sinf(rv0), c0 = __builtin_amdgcn_cosf(rv0); \
        float s1 = __builtin_amdgcn_sinf(rv1), c1 = __builtin_amdgcn_cosf(rv1); \
        float x10 = acc[i][0][r] + bias[0], x11 = acc[i][1][r] + bias[1];     \
        float x20 = acc[i][2][r] + bias[2], x21 = acc[i][3][r] + bias[3];     \
        OSt[tl * 72 + l16]      = f2b(x10 * c0 - x20 * s0);                   \
        OSt[tl * 72 + 16 + l16] = f2b(x11 * c1 - x21 * s1);                   \
        OSt[tl * 72 + 32 + l16] = f2b(x10 * s0 + x20 * c0);                   \
        OSt[tl * 72 + 48 + l16] = f2b(x11 * s1 + x21 * c1);                   \
      }                                                                       \
  }                                                                           \
  const int bb = mbase >> 11, tt0 = mbase & 2047;                             \
  const int pp = (bb << lgHG) + hh;                                           \
  if (which == 2) {                                                           \
    u16* D = Vc + ((size_t)pp * 32 + (tt0 >> 6)) * 4096;                      \
    _Pragma("unroll")                                                         \
    for (int fi = 0; fi < 8; ++fi) {                                          \
      int ks = fi >> 1, db = fi & 1;                                          \
      *(s16x8*)&D[fi * 512 + lane * 8] =                                      \
          *(const s16x8*)&OSt[(db * 32 + l31) * 72 + ks * 16 + hi * 8];       \
    }                                                                         \
  } else if (which == 1) {                                                    \
    u16* D = Kc + ((size_t)pp * 32 + (tt0 >> 6)) * 4096;                      \
    _Pragma("unroll")                                                         \
    for (int fi = 0; fi < 8; ++fi) {                                          \
      int ks = fi >> 1, kb = fi & 1;                                          \
      *(s16x8*)&D[fi * 512 + lane * 8] =                                      \
          *(const s16x8*)&OSt[(kb * 32 + l31) * 72 + ks * 16 + hi * 8];       \
    }                                                                         \
  } else {                                                                    \
    u16* D = Qc + ((size_t)pp * 64 + (tt0 >> 5)) * 2048;                      \
    _Pragma("unroll")                                                         \
    for (int fi = 0; fi < 8; ++fi) {                                          \
      int qh = fi >> 2, ks = fi & 3;                                          \
      *(s16x8*)&D[(size_t)qh * 2048 + ks * 512 + lane * 8] =                  \
          *(const s16x8*)&OSt[(qh * 32 + l31) * 72 + ks * 16 + hi * 8];       \
    }                                                                         \
  }

// ---------------------------------------------------------------------------
// Kernel 1 (slow path): fp32 in, cvt in staging. grid ((3*HG)/2, 64), 256 thr.
// ---------------------------------------------------------------------------
__global__ __launch_bounds__(256, 4) void k_qkv_rope(
    const float* __restrict__ X, const float* __restrict__ W,
    const float* __restrict__ Bias, u16* __restrict__ ws,
    int h0, int lgHB, int lgHG)
{
  __shared__ __align__(16) u16 smem[18432];   // dbuf 2x(As4096|Bs4096) | epi 4x(64x72)

  const size_t segE = 524288ull << lgHG;
  u16* Qc = ws + PWOFF;
  u16* Kc = Qc + segE;
  u16* Vc = Kc + segE;

  const int tid = threadIdx.x;
  const int w = tid >> 6, lane = tid & 63, quad = lane >> 4, l16 = lane & 15;
  const int l31 = lane & 31, hi = lane >> 5;
  const int wr = w >> 1, wc = w & 1;
  const int HB = 1 << lgHB;

  const int gx = gridDim.x;
  const int hw = blockIdx.y * gx + blockIdx.x;
  const int cpx = (gx << 6) >> 3;             // nwg/8
  const int lg = (hw & 7) * cpx + (hw >> 3);
  const int m0 = (lg / gx) * 128, n0 = (lg % gx) * 128;

  const f32x4 z4 = {0.f, 0.f, 0.f, 0.f};
  f32x4 acc[4][4];
#pragma unroll
  for (int i = 0; i < 4; ++i)
#pragma unroll
    for (int j = 0; j < 4; ++j) acc[i][j] = z4;

  const int srow = tid >> 2;
  const int scol = (tid & 3) * 8;
  const int nlogA = n0 + srow, nlogB = nlogA + 64;
  const int wrowA = (nlogA >> lgHB) * 1024 + (h0 + ((nlogA & (HB - 1)) >> 6)) * 64 + (nlogA & 63);
  const int wrowB = (nlogB >> lgHB) * 1024 + (h0 + ((nlogB & (HB - 1)) >> 6)) * 64 + (nlogB & 63);
  const float* Ag  = X + (size_t)(m0 + srow) * 1024 + scol;
  const float* BgA = W + (size_t)wrowA * 1024 + scol;
  const float* BgB = W + (size_t)wrowB * 1024 + scol;

  f32x4 la0, la1, lb0, lb1, lc0, lc1, ld0, ld1;
  QLOAD(0)
  QWRITE(smem)

  for (int k0 = 0; k0 < 1024; k0 += 32) {
    u16* Ac = smem + ((k0 >> 5) & 1) * 8192;
    if (k0 < 992) QLOAD(k0 + 32)          // issue-early
    __syncthreads();                       // buf[cur] visible; buf[cur^1] free
    s16x8 af[4], bf[4];
#pragma unroll
    for (int i = 0; i < 4; ++i)
      af[i] = *(const s16x8*)&Ac[(wr * 64 + i * 16 + l16) * 32 + quad * 8];
#pragma unroll
    for (int j = 0; j < 4; ++j)
      bf[j] = *(const s16x8*)&Ac[4096 + (wc * 64 + j * 16 + l16) * 32 + quad * 8];
#pragma unroll
    for (int i = 0; i < 4; ++i)
#pragma unroll
      for (int j = 0; j < 4; ++j)
        acc[i][j] = MFMA16(af[i], bf[j], acc[i][j]);
    if (k0 < 992) {
      u16* An = smem + ((~(k0 >> 5)) & 1) * 8192;
      QWRITE(An)                           // cvt+write late
    }
  }

  QKV_EPILOGUE
}

// ---------------------------------------------------------------------------
// Kernel 1b (fast path): bf16 X/W pre-converted -> async global_load_lds
// staging (m97 pattern).
// ---------------------------------------------------------------------------
__global__ __launch_bounds__(256, 4) void k_qkv_rope_b(
    const u16* __restrict__ Xb, const u16* __restrict__ Wb,
    const float* __restrict__ Bias, u16* __restrict__ ws,
    int h0, int lgHB, int lgHG)
{
  __shared__ __align__(16) u16 smem[18432];   // dbuf 2x(As4096|Bs4096) | epi 4x(64x72)

  const size_t segE = 524288ull << lgHG;
  u16* Qc = ws + PWOFF;
  u16* Kc = Qc + segE;
  u16* Vc = Kc + segE;

  const int tid = threadIdx.x;
  const int w = tid >> 6, lane = tid & 63, quad = lane >> 4, l16 = lane & 15;
  const int l31 = lane & 31, hi = lane >> 5;
  const int wr = w >> 1, wc = w & 1;
  const int HB = 1 << lgHB;

  const int gx = gridDim.x;
  const int hw = blockIdx.y * gx + blockIdx.x;
  const int cpx = (gx << 6) >> 3;             // nwg/8
  const int lg = (hw & 7) * cpx + (hw >> 3);
  const int m0 = (lg / gx) * 128, n0 = (lg % gx) * 128;

  const f32x4 z4 = {0.f, 0.f, 0.f, 0.f};
  f32x4 acc[4][4];
#pragma unroll
  for (int i = 0; i < 4; ++i)
#pragma unroll
    for (int j = 0; j < 4; ++j) acc[i][j] = z4;

  const int srow = tid >> 2;
  const int scol = (tid & 3) * 8;
  const int nlogA = n0 + srow, nlogB = nlogA + 64;
  const int wrowA = (nlogA >> lgHB) * 1024 + (h0 + ((nlogA & (HB - 1)) >> 6)) * 64 + (nlogA & 63);
  const int wrowB = (nlogB >> lgHB) * 1024 + (h0 + ((nlogB & (HB - 1)) >> 6)) * 64 + (nlogB & 63);
  const u16* Agb  = Xb + (size_t)(m0 + srow) * 1024 + scol;
  const u16* BgAb = Wb + (size_t)wrowA * 1024 + scol;
  const u16* BgBb = Wb + (size_t)wrowB * 1024 + scol;

  // prologue: async-stage tile 0 into buf 0
  QISSUEB(0, smem)

  for (int k0 = 0; k0 < 1024; k0 += 32) {
    u16* Ac = smem + ((k0 >> 5) & 1) * 8192;
    __syncthreads();                       // drains buf[cur] loads; frees other
    if (k0 < 992) {
      u16* An = smem + ((~(k0 >> 5)) & 1) * 8192;
      QISSUEB(k0 + 32, An)                 // async, overlaps MFMA below
    }
    s16x8 af[4], bf[4];
#pragma unroll
    for (int i = 0; i < 4; ++i)
      af[i] = *(const s16x8*)&Ac[(wr * 64 + i * 16 + l16) * 32 + quad * 8];
#pragma unroll
    for (int j = 0; j < 4; ++j)
      bf[j] = *(const s16x8*)&Ac[4096 + (wc * 64 + j * 16 + l16) * 32 + quad * 8];
#pragma unroll
    for (int i = 0; i < 4; ++i)
#pragma unroll
      for (int j = 0; j < 4; ++j)
        acc[i][j] = MFMA16(af[i], bf[j], acc[i][j]);
  }

  QKV_EPILOGUE
}

// ---------------------------------------------------------------------------
// Kernel 2: flash attention, 2 softmax states per wave (r12-proven, 104 µs,
// VGPR 116 at (256,2)). Frozen.
// grid (8, 4*HG), 256 thr.
// ---------------------------------------------------------------------------
__global__ __launch_bounds__(256, 2) void k_attn(
    u16* __restrict__ ws, u16* __restrict__ AO, int h0, int lgHG)
{
  __shared__ float redL[4][32];          // per-wave alpha / inv-li broadcast

  const size_t segE = 524288ull << lgHG;
  const u16* Qg = ws + PWOFF;
  const u16* Kg = Qg + segE;
  const u16* Vg = Kg + segE;

  const int tid = threadIdx.x;
  const int w = tid >> 6, lane = tid & 63;
  const int l31 = lane & 31, hi = lane >> 5;

  // XCD swizzle: n = by*8 + bx; xcd = n&7 gets heads [xcd*P/8, ...)
  const int P = 4 << lgHG;
  const int n = blockIdx.y * 8 + blockIdx.x;
  const int mm = n >> 3;
  const int p  = (n & 7) * (P >> 3) + (mm >> 3);
  const int qt = mm & 7;                 // 256-row q tile

  const u16* Kb = Kg + (size_t)p * 131072;
  const u16* Vb = Vg + (size_t)p * 131072;
  const int q0A = qt * 256 + w * 32;
  const int q0B = q0A + 128;

  // Q fragments: frag-major; qt32 = q0/32
  const u16* QtA = Qg + (size_t)p * 131072 + (size_t)(qt * 8 + w) * 2048;
  const u16* QtB = QtA + 4 * 2048;
  s16x8 qfA[4], qfB[4];
#pragma unroll
  for (int ks = 0; ks < 4; ++ks) {
    qfA[ks] = *(const s16x8*)&QtA[ks * 512 + lane * 8];
    qfB[ks] = *(const s16x8*)&QtB[ks * 512 + lane * 8];
  }

  f32x16 oA0, oA1, oB0, oB1;             // O[q=crow(r,hi)][d=l31 (+32)]
#pragma unroll
  for (int r = 0; r < 16; ++r) { oA0[r] = 0.f; oA1[r] = 0.f; oB0[r] = 0.f; oB1[r] = 0.f; }
  float mA = -1e30f, lA = 0.f, mB = -1e30f, lB = 0.f;
  const float C = 0.1803368801f;         // 0.125 * log2(e)

  for (int kt = 0; kt < 32; ++kt) {
    const u16* Kt = Kb + (size_t)kt * 4096;
    const u16* Vt = Vb + (size_t)kt * 4096;
    s16x8 kfA[4], kfB[4], vfA[4], vfB[4];
#pragma unroll
    for (int ks = 0; ks < 4; ++ks) {
      kfA[ks] = *(const s16x8*)&Kt[(ks * 2 + 0) * 512 + lane * 8];
      kfB[ks] = *(const s16x8*)&Kt[(ks * 2 + 1) * 512 + lane * 8];
    }
#pragma unroll
    for (int ks = 0; ks < 4; ++ks) {
      vfA[ks] = *(const s16x8*)&Vt[(ks * 2 + 0) * 512 + lane * 8];
      vfB[ks] = *(const s16x8*)&Vt[(ks * 2 + 1) * 512 + lane * 8];
    }

    // both QK^T first (kf dies early; 16 back-to-back MFMAs)
    f32x16 sA0, sA1, sB0, sB1;
    QKT_P(qfA, kfA, kfB, sA0, sA1)
    QKT_P(qfB, kfA, kfB, sB0, sB1)

    {
      s16x8 pa0, pa1, pa2, pa3;
      SMAX_P(sA0, sA1, pa0, pa1, pa2, pa3, mA, lA, oA0, oA1)
      PV_P(pa0, pa1, pa2, pa3, vfA, vfB, oA0, oA1)
    }
    {
      s16x8 pa0, pa1, pa2, pa3;
      SMAX_P(sB0, sB1, pa0, pa1, pa2, pa3, mB, lB, oB0, oB1)
      PV_P(pa0, pa1, pa2, pa3, vfA, vfB, oB0, oB1)
    }
  }

  const int p_glob = (p >> lgHG) * 16 + h0 + (p & ((1 << lgHG) - 1));
  ATT_EPI(lA, oA0, oA1, q0A)
  ATT_EPI(lB, oB0, oB1, q0B)
}

// k_proj async staging: 4 x global_load_lds(16B) per thread per K-step.
// LDS regions (u16): a0 @0 (rows 0-63), a1 @2048 (rows 64-127),
// b0 @4096, b1 @6144; buffer stride 8192 u16.
#define PISSUE(K, BUF) {                                                     \
    const int c0_ = (K) + scol;                                              \
    const size_t aoff_ = (size_t)(c0_ >> 6) * 131072 + (c0_ & 63);           \
    GLD16(Abase + aoff_,         (BUF) + w * 512);                           \
    GLD16(Abase + 4096 + aoff_,  (BUF) + 2048 + w * 512);                    \
    GLD16(Bg + (K),              (BUF) + 4096 + w * 512);                    \
    GLD16(Bg + 65536 + (K),      (BUF) + 6144 + w * 512);                    \
  }

// ---------------------------------------------------------------------------
// Kernel 3: Out(fp32) = AO @ proj_w^T + proj_b. r13: 128x128 tile (the
// proven qkv main loop: 16 MFMA/wave/K-step, acc 4x4), grid (8, 64) = 512
// blocks. Async gload_lds dbuf, one barrier/K-step. Epilogue staged in two
// 32-row halves per wave (8KB f32 each, 32KB total overlay on the dbuf).
// ---------------------------------------------------------------------------
__global__ __launch_bounds__(256, 4) void k_proj(
    const u16* __restrict__ AO, const u16* __restrict__ W,
    const float* __restrict__ Bias, float* __restrict__ Out)
{
  __shared__ __align__(16) u16 smem[16384];   // dbuf 2x8192 u16 (32KB); epi f32 overlay

  const int tid = threadIdx.x;
  const int w = tid >> 6, lane = tid & 63, quad = lane >> 4, l16 = lane & 15;
  const int wr = w >> 1, wc = w & 1;

  // XCD-grouped bijective swizzle (nwg = 512): 8 M-panels x 8 N per XCD chunk.
  const int hw = blockIdx.y * 8 + blockIdx.x;
  const int lg = (hw & 7) * 64 + (hw >> 3);
  const int m0 = (lg >> 3) * 128, n0 = (lg & 7) * 128;

  const f32x4 z4 = {0.f, 0.f, 0.f, 0.f};
  f32x4 acc[4][4];
#pragma unroll
  for (int i = 0; i < 4; ++i)
#pragma unroll
    for (int j = 0; j < 4; ++j) acc[i][j] = z4;

  const int srow = tid >> 2;                  // 0..63
  const int scol = (tid & 3) * 8;
  const int bb = m0 >> 11, tt = m0 & 2047;    // 128-row tile within one batch
  const u16* Abase = AO + (size_t)bb * 2097152 + (size_t)(tt + srow) * 64;
  const u16* Bg = W + (size_t)(n0 + srow) * 1024 + scol;

  // prologue: async-stage tile 0 into buf 0
  PISSUE(0, smem)

  for (int k0 = 0; k0 < 1024; k0 += 32) {
    u16* Ac = smem + ((k0 >> 5) & 1) * 8192;
    __syncthreads();                       // drains buf[cur] loads; frees other
    if (k0 < 992) {
      u16* An = smem + ((~(k0 >> 5)) & 1) * 8192;
      PISSUE(k0 + 32, An)                  // async, overlaps MFMA below
    }
    s16x8 af[4], bf[4];
#pragma unroll
    for (int i = 0; i < 4; ++i)
      af[i] = *(const s16x8*)&Ac[(wr * 64 + i * 16 + l16) * 32 + quad * 8];
#pragma unroll
    for (int j = 0; j < 4; ++j)
      bf[j] = *(const s16x8*)&Ac[4096 + (wc * 64 + j * 16 + l16) * 32 + quad * 8];
#pragma unroll
    for (int i = 0; i < 4; ++i)
#pragma unroll
      for (int j = 0; j < 4; ++j)
        acc[i][j] = MFMA16(af[i], bf[j], acc[i][j]);
  }

  const int ncol = n0 + wc * 64;
  float bias[4];
#pragma unroll
  for (int j = 0; j < 4; ++j) bias[j] = Bias[ncol + j * 16 + l16];

  __syncthreads();                      // all waves done with staging bufs
  float* OSw = (float*)smem + w * 2048; // per-wave 32 rows x 64 cols f32 (8 KB)
#pragma unroll
  for (int h = 0; h < 2; ++h) {
#pragma unroll
    for (int ii = 0; ii < 2; ++ii) {
      int i = h * 2 + ii;
#pragma unroll
      for (int j = 0; j < 4; ++j)
#pragma unroll
        for (int r = 0; r < 4; ++r) {
          int tl = ii * 16 + quad * 4 + r;
          OSw[tl * 64 + j * 16 + l16] = acc[i][j][r] + bias[j];
        }
    }
    // same-wave ordering; wide stores: 16B/lane, 256B per 16 lanes
#pragma unroll
    for (int itr = 0; itr < 8; ++itr) {
      int task = itr * 64 + lane;
      int tl = task >> 4, g = task & 15;
      int row = m0 + wr * 64 + h * 32 + tl;
      *(f32x4*)&Out[(size_t)row * 1024 + ncol + g * 4] =
          *(const f32x4*)&OSw[tl * 64 + g * 4];
    }
  }
}

// ---------------------------------------------------------------------------
extern "C" void kernel_launch(void* const* d_in, const int* in_sizes, int n_in,
                              void* d_out, int out_size, void* d_ws, size_t ws_size,
                              hipStream_t stream) {
  const float* X    = (const float*)d_in[0];   // [4,2048,1024] fp32
  const float* QKVW = (const float*)d_in[1];   // [3072,1024]
  const float* QKVB = (const float*)d_in[2];   // [3072]
  const float* PW   = (const float*)d_in[3];   // [1024,1024]
  const float* PB   = (const float*)d_in[4];   // [1024]
  float* Out = (float*)d_out;                  // [4,2048,1024] fp32
  u16* ws = (u16*)d_ws;

  // ws (bytes): HG16: PWOFF+3*segE = 52.4MB (AO aliases Qc);
  // HG<16: + dedicated AO. Fast path: +Xb(16.8MB)+Wb(6.3MB) = 75.5MB.
  int HG, lgHG, ok = 1;
  if      (ws_size >= 52428800ull) { HG = 16; lgHG = 4; }
  else if (ws_size >= 44040192ull) { HG = 8;  lgHG = 3; }
  else if (ws_size >= 31457280ull) { HG = 4;  lgHG = 2; }
  else if (ws_size >= 25165824ull) { HG = 2;  lgHG = 1; }
  else                             { HG = 2;  lgHG = 1; ok = 0; }

  if (!ok) {
    k_beacon<<<dim3(4096), 256, 0, stream>>>(Out, (unsigned long long)ws_size);
    return;
  }

  const size_t segE = 524288ull << lgHG;
  u16* Qc = ws + PWOFF;
  u16* AO = (HG == 16) ? Qc : (Qc + 3 * segE);
  const int lgHB = lgHG + 6;

  // fast path: pre-convert X and QKVW to bf16 (needs 75.5MB total ws)
  const bool fast = (HG == 16) && (ws_size >= 75497472ull);
  u16* Xb = Qc + 3 * segE;                 // 8,388,608 elems
  u16* Wb = Xb + 8388608ull;               // 3,145,728 elems

  if (fast)
    k_convert_all<<<dim3(6144), 256, 0, stream>>>(PW, X, QKVW, ws, Xb);
  else
    k_convert_pw<<<dim3(512), 256, 0, stream>>>(PW, ws);

  const int chunks = 16 / HG;
  for (int c = 0; c < chunks; ++c) {
    int h0 = c * HG;
    if (fast)
      k_qkv_rope_b<<<dim3((3 * HG) / 2, 64), 256, 0, stream>>>(
          Xb, Wb, QKVB, ws, h0, lgHB, lgHG);
    else
      k_qkv_rope<<<dim3((3 * HG) / 2, 64), 256, 0, stream>>>(
          X, QKVW, QKVB, ws, h0, lgHB, lgHG);
    k_attn<<<dim3(8, 4 * HG), 256, 0, stream>>>(ws, AO, h0, lgHG);
  }
  k_proj<<<dim3(8, 64), 256, 0, stream>>>(AO, ws, PB, Out);
}